// Round 2
// baseline (1275.555 us; speedup 1.0000x reference)
//
#include <hip/hip_runtime.h>

#define HW 2304   // 48*48

// ---------------------------------------------------------------------------
// Sobel edge magnitude on x3 (C=1), SAME zero padding.  [4,48,48] -> [4,2304]
// ---------------------------------------------------------------------------
__global__ __launch_bounds__(256) void edge_kernel(const float* __restrict__ x3,
                                                   float* __restrict__ edge) {
    int idx = blockIdx.x * 256 + threadIdx.x;   // < 9216
    int b = idx / HW;
    int j = idx % HW;
    int y = j / 48, x = j % 48;
    const float* p = x3 + b * HW;
    auto at = [&](int yy, int xx) -> float {
        return (yy >= 0 && yy < 48 && xx >= 0 && xx < 48) ? p[yy * 48 + xx] : 0.f;
    };
    float a00 = at(y - 1, x - 1), a01 = at(y - 1, x), a02 = at(y - 1, x + 1);
    float a10 = at(y, x - 1),                         a12 = at(y, x + 1);
    float a20 = at(y + 1, x - 1), a21 = at(y + 1, x), a22 = at(y + 1, x + 1);
    float ex = (a02 - a00) + 2.f * (a12 - a10) + (a22 - a20);
    float ey = (a20 - a00) + 2.f * (a21 - a01) + (a22 - a02);
    edge[idx] = sqrtf(ex * ex + ey * ey);
}

// ---------------------------------------------------------------------------
// conv3x3 (SAME, stride 1) + BatchNorm(eval) + LeakyReLU(0.01)
// in:  [4][CIN][48][48]   w: [64][CIN][3][3]   out: [4][64][2304]
// Block: 256 thr = 16x16 spatial tile, 8 output channels per block.
// Grid: 4 b * 9 tiles * 8 cout-groups = 288 (XCD-swizzled).
// Input slice double-buffered in LDS (1 barrier per cin); weights read
// wave-uniform from global -> scalar loads; BN folded into epilogue.
// ---------------------------------------------------------------------------
template <int CIN>
__global__ __launch_bounds__(256) void conv_bn_lrelu(
    const float* __restrict__ in, const float* __restrict__ w,
    const float* __restrict__ bias,
    const float* __restrict__ bng, const float* __restrict__ bnb,
    const float* __restrict__ bnm, const float* __restrict__ bnv,
    float* __restrict__ out) {
    // bijective XCD swizzle (288 % 8 == 0): chunk of 36 contiguous logical
    // blocks per XCD -> each XCD touches at most 2 batches' activations.
    int lb = blockIdx.x;
    int blk = (lb & 7) * 36 + (lb >> 3);

    const int cg   = blk & 7;          // cout group (8 groups of 8)
    const int tile = (blk >> 3) % 9;   // 3x3 spatial tiles of 16x16
    const int b    = blk / 72;
    const int tx0 = (tile % 3) * 16, ty0 = (tile / 3) * 16;
    const int tid = threadIdx.x;
    const int tx = tid & 15, ty = tid >> 4;

    __shared__ float sl[2][18][20];

    float acc[8];
#pragma unroll
    for (int k = 0; k < 8; k++) acc[k] = 0.f;

    const float* wbase = w + cg * 8 * CIN * 9;

    // initial slice (cin = 0)
    {
        const float* ip = in + (b * CIN) * HW;
        for (int e = tid; e < 324; e += 256) {
            int ly = e / 18, lx = e % 18;
            int gy = ty0 + ly - 1, gx = tx0 + lx - 1;
            float v = 0.f;
            if (gy >= 0 && gy < 48 && gx >= 0 && gx < 48) v = ip[gy * 48 + gx];
            sl[0][ly][lx] = v;
        }
    }
    __syncthreads();

    for (int cin = 0; cin < CIN; ++cin) {
        if (cin + 1 < CIN) {  // prefetch next slice into the other buffer
            const float* ip = in + (b * CIN + cin + 1) * HW;
            int bufn = (cin + 1) & 1;
            for (int e = tid; e < 324; e += 256) {
                int ly = e / 18, lx = e % 18;
                int gy = ty0 + ly - 1, gx = tx0 + lx - 1;
                float v = 0.f;
                if (gy >= 0 && gy < 48 && gx >= 0 && gx < 48) v = ip[gy * 48 + gx];
                sl[bufn][ly][lx] = v;
            }
        }
        const int s = cin & 1;
        float xv[9];
#pragma unroll
        for (int dy = 0; dy < 3; dy++)
#pragma unroll
            for (int dx = 0; dx < 3; dx++) xv[dy * 3 + dx] = sl[s][ty + dy][tx + dx];

        const float* wc = wbase + cin * 9;
#pragma unroll
        for (int k = 0; k < 8; k++) {
            const float* wk = wc + k * CIN * 9;  // wave-uniform -> s_loads
            float a = acc[k];
#pragma unroll
            for (int d = 0; d < 9; d++) a = fmaf(wk[d], xv[d], a);
            acc[k] = a;
        }
        __syncthreads();
    }

    const int oy = ty0 + ty, ox = tx0 + tx;
#pragma unroll
    for (int k = 0; k < 8; k++) {
        int o = cg * 8 + k;
        float sc = bng[o] * rsqrtf(bnv[o] + 1e-5f);
        float sh = bnb[o] - bnm[o] * sc;
        float y = fmaf(acc[k] + bias[o], sc, sh);
        y = y > 0.f ? y : 0.01f * y;
        out[(b * 64 + o) * HW + oy * 48 + ox] = y;
    }
}

// ---------------------------------------------------------------------------
// Per-position value vectors (1x1 conv 64->8) and squared norms.
// d: [4][64][2304]  ->  vbuf[m][b][j][8], rbuf[m][b][j]
// ---------------------------------------------------------------------------
__global__ __launch_bounds__(256) void value_r_kernel(
    const float* __restrict__ d1, const float* __restrict__ d2,
    const float* __restrict__ d3, const float* __restrict__ Wv,
    const float* __restrict__ bv, float* __restrict__ vbuf,
    float* __restrict__ rbuf) {
    int blk = blockIdx.x;          // 3*4*9 = 108
    int jt = blk % 9;
    int b = (blk / 9) % 4;
    int m = blk / 36;
    int j = jt * 256 + threadIdx.x;
    const float* dm = (m == 0) ? d1 : (m == 1) ? d2 : d3;
    const float* dp = dm + (b * 64) * HW + j;
    float acc[8];
#pragma unroll
    for (int k = 0; k < 8; k++) acc[k] = 0.f;
    float r = 0.f;
    for (int c = 0; c < 64; c++) {
        float x = dp[c * HW];
        r = fmaf(x, x, r);
#pragma unroll
        for (int k = 0; k < 8; k++) acc[k] = fmaf(x, Wv[k * 64 + c], acc[k]);
    }
    float* vp = vbuf + ((m * 4 + b) * HW + j) * 8;
#pragma unroll
    for (int k = 0; k < 8; k++) vp[k] = acc[k] + bv[k];
    rbuf[(m * 4 + b) * HW + j] = r;
}

// ---------------------------------------------------------------------------
// Fused similarity-attention.  For each (b, 32-row i-tile):
//   loop j in tiles of 64: G_m[i][j] on the fly -> a_m = exp(-d2/(2s^2))
//   -> 3 linear combos -> accumulate PV into [32][8] x 3 (incl. gamma scale).
// No [HW,HW] matrix is ever materialized.
// threads 256 = 16 tj x 16 ti; micro-tile 2 rows x 4 cols per thread.
// ---------------------------------------------------------------------------
__global__ __launch_bounds__(256) void attn_kernel(
    const float* __restrict__ d1, const float* __restrict__ d2,
    const float* __restrict__ d3, const float* __restrict__ vbuf,
    const float* __restrict__ rbuf, const float* __restrict__ gam,
    float* __restrict__ attbuf) {
    // bijective XCD swizzle: 288 blocks, 36 per XCD -> each XCD's working set
    // is one batch's d1/d2/d3 (1.77 MB) -> fits the 4 MB per-XCD L2.
    int lb = blockIdx.x;
    int blk = (lb & 7) * 36 + (lb >> 3);
    const int it = blk % 72;
    const int b = blk / 72;
    const int i0 = it * 32;
    const int tid = threadIdx.x;
    const int tj = tid & 15;
    const int ti = tid >> 4;

    __shared__ float Fi[3][64][32];
    __shared__ float Ri[3][32];

    for (int e = tid; e < 3 * 64 * 32; e += 256) {
        int m = e >> 11;
        int c = (e >> 5) & 63;
        int i = e & 31;
        const float* dm = (m == 0) ? d1 : (m == 1) ? d2 : d3;
        Fi[m][c][i] = dm[(b * 64 + c) * HW + i0 + i];
    }
    if (tid < 96) {
        int m = tid >> 5, i = tid & 31;
        Ri[m][i] = rbuf[(m * 4 + b) * HW + i0 + i];
    }

    float g0 = gam[0], g1 = gam[1], g2 = gam[2];
    float inv0 = 1.f / (2.f * g0 * g0);
    float inv1 = 1.f / (2.f * g1 * g1);
    float inv2 = 1.f / (2.f * g2 * g2);
    float g6 = gam[6], g7 = gam[7], g8 = gam[8];
    float c00 = g6,       c01 = g7 + 1.f, c02 = g8 + 1.f;
    float c10 = g6 + 1.f, c11 = g7,       c12 = g8 + 1.f;
    float c20 = g6 + 1.f, c21 = g7 + 1.f, c22 = g8;

    __syncthreads();

    float ri0[2], ri1[2], ri2[2];
    ri0[0] = Ri[0][2 * ti]; ri0[1] = Ri[0][2 * ti + 1];
    ri1[0] = Ri[1][2 * ti]; ri1[1] = Ri[1][2 * ti + 1];
    ri2[0] = Ri[2][2 * ti]; ri2[1] = Ri[2][2 * ti + 1];

    float pv[3][2][8];
#pragma unroll
    for (int m = 0; m < 3; m++)
#pragma unroll
        for (int r = 0; r < 2; r++)
#pragma unroll
            for (int k = 0; k < 8; k++) pv[m][r][k] = 0.f;

    const float* q0 = d1 + (b * 64) * HW + 4 * tj;
    const float* q1 = d2 + (b * 64) * HW + 4 * tj;
    const float* q2 = d3 + (b * 64) * HW + 4 * tj;
    const float* rb0 = rbuf + (0 * 4 + b) * HW + 4 * tj;
    const float* rb1 = rbuf + (1 * 4 + b) * HW + 4 * tj;
    const float* rb2 = rbuf + (2 * 4 + b) * HW + 4 * tj;

    for (int jt = 0; jt < 36; ++jt) {
        const int j0 = jt * 64;
        float fa0[2][4], fa1[2][4], fa2[2][4];
#pragma unroll
        for (int r = 0; r < 2; r++)
#pragma unroll
            for (int q = 0; q < 4; q++) { fa0[r][q] = 0.f; fa1[r][q] = 0.f; fa2[r][q] = 0.f; }

#pragma unroll 2
        for (int c = 0; c < 64; ++c) {
            const float2 fi0 = *(const float2*)&Fi[0][c][2 * ti];
            const float2 fi1 = *(const float2*)&Fi[1][c][2 * ti];
            const float2 fi2 = *(const float2*)&Fi[2][c][2 * ti];
            float4 fj0 = *(const float4*)(q0 + c * HW + j0);
            float4 fj1 = *(const float4*)(q1 + c * HW + j0);
            float4 fj2 = *(const float4*)(q2 + c * HW + j0);
            float a0[4] = {fj0.x, fj0.y, fj0.z, fj0.w};
            float a1[4] = {fj1.x, fj1.y, fj1.z, fj1.w};
            float a2[4] = {fj2.x, fj2.y, fj2.z, fj2.w};
#pragma unroll
            for (int q = 0; q < 4; q++) {
                fa0[0][q] = fmaf(fi0.x, a0[q], fa0[0][q]);
                fa0[1][q] = fmaf(fi0.y, a0[q], fa0[1][q]);
                fa1[0][q] = fmaf(fi1.x, a1[q], fa1[0][q]);
                fa1[1][q] = fmaf(fi1.y, a1[q], fa1[1][q]);
                fa2[0][q] = fmaf(fi2.x, a2[q], fa2[0][q]);
                fa2[1][q] = fmaf(fi2.y, a2[q], fa2[1][q]);
            }
        }

        float4 rj0 = *(const float4*)(rb0 + j0);
        float4 rj1 = *(const float4*)(rb1 + j0);
        float4 rj2 = *(const float4*)(rb2 + j0);
        float rj0a[4] = {rj0.x, rj0.y, rj0.z, rj0.w};
        float rj1a[4] = {rj1.x, rj1.y, rj1.z, rj1.w};
        float rj2a[4] = {rj2.x, rj2.y, rj2.z, rj2.w};

#pragma unroll
        for (int q = 0; q < 4; q++) {
            const int j = j0 + 4 * tj + q;
            const float* vp0 = vbuf + ((0 * 4 + b) * HW + j) * 8;
            const float* vp1 = vbuf + ((1 * 4 + b) * HW + j) * 8;
            const float* vp2 = vbuf + ((2 * 4 + b) * HW + j) * 8;
            float4 v0a = *(const float4*)vp0, v0b = *(const float4*)(vp0 + 4);
            float4 v1a = *(const float4*)vp1, v1b = *(const float4*)(vp1 + 4);
            float4 v2a = *(const float4*)vp2, v2b = *(const float4*)(vp2 + 4);
            float v0[8] = {v0a.x, v0a.y, v0a.z, v0a.w, v0b.x, v0b.y, v0b.z, v0b.w};
            float v1[8] = {v1a.x, v1a.y, v1a.z, v1a.w, v1b.x, v1b.y, v1b.z, v1b.w};
            float v2[8] = {v2a.x, v2a.y, v2a.z, v2a.w, v2b.x, v2b.y, v2b.z, v2b.w};
#pragma unroll
            for (int r = 0; r < 2; r++) {
                float t0 = fmaxf(ri0[r] + rj0a[q] - 2.f * fa0[r][q], 0.f);
                float t1 = fmaxf(ri1[r] + rj1a[q] - 2.f * fa1[r][q], 0.f);
                float t2 = fmaxf(ri2[r] + rj2a[q] - 2.f * fa2[r][q], 0.f);
                float a0e = __expf(-t0 * inv0);
                float a1e = __expf(-t1 * inv1);
                float a2e = __expf(-t2 * inv2);
                float u0 = c00 * a0e + c01 * a1e + c02 * a2e;
                float u1 = c10 * a0e + c11 * a1e + c12 * a2e;
                float u2 = c20 * a0e + c21 * a1e + c22 * a2e;
#pragma unroll
                for (int k = 0; k < 8; k++) {
                    pv[0][r][k] = fmaf(u0, v0[k], pv[0][r][k]);
                    pv[1][r][k] = fmaf(u1, v1[k], pv[1][r][k]);
                    pv[2][r][k] = fmaf(u2, v2[k], pv[2][r][k]);
                }
            }
        }
    }

    // reduce across the 16 tj lanes (one row lives in 16 contiguous lanes)
    float gs0 = gam[3], gs1 = gam[4], gs2 = gam[5];
#pragma unroll
    for (int m = 0; m < 3; m++) {
        float gs = (m == 0) ? gs0 : (m == 1) ? gs1 : gs2;
#pragma unroll
        for (int r = 0; r < 2; r++)
#pragma unroll
            for (int k = 0; k < 8; k++) {
                float v = pv[m][r][k] * gs;
                v += __shfl_xor(v, 1, 16);
                v += __shfl_xor(v, 2, 16);
                v += __shfl_xor(v, 4, 16);
                v += __shfl_xor(v, 8, 16);
                if (tj == 0)
                    attbuf[((m * 4 + b) * HW + i0 + 2 * ti + r) * 8 + k] = v;
            }
    }
}

// ---------------------------------------------------------------------------
// out[m][b][c][j] = d_m[b][c][j] * (att_m[b][j][:] . Wo[c][:] + bo[c]) + edge[b][j]
// ---------------------------------------------------------------------------
__global__ __launch_bounds__(256) void final_kernel(
    const float* __restrict__ d1, const float* __restrict__ d2,
    const float* __restrict__ d3, const float* __restrict__ attbuf,
    const float* __restrict__ Wo, const float* __restrict__ bo,
    const float* __restrict__ edge, float* __restrict__ out) {
    int blk = blockIdx.x;  // 3*4*64*9 = 6912
    int jt = blk % 9;
    int c = (blk / 9) % 64;
    int b = (blk / (9 * 64)) % 4;
    int m = blk / (9 * 64 * 4);
    int j = jt * 256 + threadIdx.x;
    const float* dm = (m == 0) ? d1 : (m == 1) ? d2 : d3;
    const float* ap = attbuf + ((m * 4 + b) * HW + j) * 8;
    float4 aa = *(const float4*)ap, ab = *(const float4*)(ap + 4);
    float av[8] = {aa.x, aa.y, aa.z, aa.w, ab.x, ab.y, ab.z, ab.w};
    float s = bo[c];
#pragma unroll
    for (int k = 0; k < 8; k++) s = fmaf(av[k], Wo[c * 8 + k], s);
    float val = fmaf(dm[(b * 64 + c) * HW + j], s, edge[b * HW + j]);
    out[((m * 4 + b) * 64 + c) * HW + j] = val;
}

// ---------------------------------------------------------------------------
extern "C" void kernel_launch(void* const* d_in, const int* in_sizes, int n_in,
                              void* d_out, int out_size, void* d_ws, size_t ws_size,
                              hipStream_t stream) {
    (void)in_sizes; (void)n_in; (void)out_size; (void)ws_size;
    const float* x1   = (const float*)d_in[0];
    const float* x2   = (const float*)d_in[1];
    const float* x3   = (const float*)d_in[2];
    const float* Wc1  = (const float*)d_in[3];
    const float* bc1  = (const float*)d_in[4];
    const float* Wc2  = (const float*)d_in[5];
    const float* bc2  = (const float*)d_in[6];
    const float* Wc3  = (const float*)d_in[7];
    const float* bc3  = (const float*)d_in[8];
    const float* bnf_g = (const float*)d_in[9];
    const float* bnf_b = (const float*)d_in[10];
    const float* bnf_m = (const float*)d_in[11];
    const float* bnf_v = (const float*)d_in[12];
    const float* Wm   = (const float*)d_in[13];
    const float* bm   = (const float*)d_in[14];
    const float* bnm_g = (const float*)d_in[15];
    const float* bnm_b = (const float*)d_in[16];
    const float* bnm_m = (const float*)d_in[17];
    const float* bnm_v = (const float*)d_in[18];
    const float* Wv   = (const float*)d_in[19];
    const float* bv   = (const float*)d_in[20];
    const float* Wo   = (const float*)d_in[21];
    const float* bo   = (const float*)d_in[22];
    const float* gam  = (const float*)d_in[23];

    float* ws = (float*)d_ws;
    const int NB = 4 * 64 * HW;  // 589824 floats per activation buffer
    float* A1 = ws;
    float* A2 = A1 + NB;
    float* B1 = A2 + NB;
    float* B2 = B1 + NB;
    float* C1 = B2 + NB;
    float* C2 = C1 + NB;
    float* edge = C2 + NB;               // 4*2304
    float* vbuf = edge + 4 * HW;         // 3*4*2304*8
    float* rbuf = vbuf + 3 * 4 * HW * 8; // 3*4*2304
    float* attb = rbuf + 3 * 4 * HW;     // 3*4*2304*8

    const int WMS = 64 * 64 * 9;  // Wm per-conv stride

    edge_kernel<<<36, 256, 0, stream>>>(x3, edge);

    conv_bn_lrelu<144><<<288, 256, 0, stream>>>(x1, Wc1, bc1, bnf_g, bnf_b, bnf_m, bnf_v, A1);
    conv_bn_lrelu<21><<<288, 256, 0, stream>>>(x2, Wc2, bc2, bnf_g + 64, bnf_b + 64, bnf_m + 64, bnf_v + 64, B1);
    conv_bn_lrelu<1><<<288, 256, 0, stream>>>(x3, Wc3, bc3, bnf_g + 128, bnf_b + 128, bnf_m + 128, bnf_v + 128, C1);

    conv_bn_lrelu<64><<<288, 256, 0, stream>>>(A1, Wm + 0 * WMS, bm + 0,   bnm_g + 0,   bnm_b + 0,   bnm_m + 0,   bnm_v + 0,   A2);
    conv_bn_lrelu<64><<<288, 256, 0, stream>>>(A2, Wm + 1 * WMS, bm + 64,  bnm_g + 64,  bnm_b + 64,  bnm_m + 64,  bnm_v + 64,  A1);
    conv_bn_lrelu<64><<<288, 256, 0, stream>>>(B1, Wm + 2 * WMS, bm + 128, bnm_g + 128, bnm_b + 128, bnm_m + 128, bnm_v + 128, B2);
    conv_bn_lrelu<64><<<288, 256, 0, stream>>>(B2, Wm + 3 * WMS, bm + 192, bnm_g + 192, bnm_b + 192, bnm_m + 192, bnm_v + 192, B1);
    conv_bn_lrelu<64><<<288, 256, 0, stream>>>(C1, Wm + 4 * WMS, bm + 256, bnm_g + 256, bnm_b + 256, bnm_m + 256, bnm_v + 256, C2);
    conv_bn_lrelu<64><<<288, 256, 0, stream>>>(C2, Wm + 5 * WMS, bm + 320, bnm_g + 320, bnm_b + 320, bnm_m + 320, bnm_v + 320, C1);

    value_r_kernel<<<108, 256, 0, stream>>>(A1, B1, C1, Wv, bv, vbuf, rbuf);
    attn_kernel<<<288, 256, 0, stream>>>(A1, B1, C1, vbuf, rbuf, gam, attb);
    final_kernel<<<6912, 256, 0, stream>>>(A1, B1, C1, attb, Wo, bo, edge, (float*)d_out);
}

// Round 4
// 1023.174 us; speedup vs baseline: 1.2467x; 1.2467x over previous
//
#include <hip/hip_runtime.h>

#define HW 2304   // 48*48

// ---------------------------------------------------------------------------
// Zero the attention accumulator (attn_kernel atomically adds partials).
// 221184 floats -> 216 blocks x 256 thr x float4.
// ---------------------------------------------------------------------------
__global__ __launch_bounds__(256) void zero_kernel(float4* __restrict__ p) {
    p[blockIdx.x * 256 + threadIdx.x] = make_float4(0.f, 0.f, 0.f, 0.f);
}

// ---------------------------------------------------------------------------
// Sobel edge magnitude on x3 (C=1), SAME zero padding.  [4,48,48] -> [4,2304]
// ---------------------------------------------------------------------------
__global__ __launch_bounds__(256) void edge_kernel(const float* __restrict__ x3,
                                                   float* __restrict__ edge) {
    int idx = blockIdx.x * 256 + threadIdx.x;   // < 9216
    int b = idx / HW;
    int j = idx % HW;
    int y = j / 48, x = j % 48;
    const float* p = x3 + b * HW;
    auto at = [&](int yy, int xx) -> float {
        return (yy >= 0 && yy < 48 && xx >= 0 && xx < 48) ? p[yy * 48 + xx] : 0.f;
    };
    float a00 = at(y - 1, x - 1), a01 = at(y - 1, x), a02 = at(y - 1, x + 1);
    float a10 = at(y, x - 1),                         a12 = at(y, x + 1);
    float a20 = at(y + 1, x - 1), a21 = at(y + 1, x), a22 = at(y + 1, x + 1);
    float ex = (a02 - a00) + 2.f * (a12 - a10) + (a22 - a20);
    float ey = (a20 - a00) + 2.f * (a21 - a01) + (a22 - a02);
    edge[idx] = sqrtf(ex * ex + ey * ey);
}

// ---------------------------------------------------------------------------
// conv3x3 (SAME, stride 1) + BatchNorm(eval) + LeakyReLU(0.01)
// in:  [4][CIN][48][48]   w: [64][CIN][3][3]   out: [4][64][2304]
// Block: 256 thr = 16x16 spatial tile, 2 output channels per block.
// Grid: 4 b * 9 tiles * 32 cout-groups = 1152 (XCD-swizzled) -> 4.5 blocks/CU.
// ---------------------------------------------------------------------------
template <int CIN>
__global__ __launch_bounds__(256) void conv_bn_lrelu(
    const float* __restrict__ in, const float* __restrict__ w,
    const float* __restrict__ bias,
    const float* __restrict__ bng, const float* __restrict__ bnb,
    const float* __restrict__ bnm, const float* __restrict__ bnv,
    float* __restrict__ out) {
    // bijective XCD swizzle (1152 % 8 == 0): 144 contiguous logical blocks
    // per XCD, b-major -> within-batch L2 locality.
    int lb = blockIdx.x;
    int blk = (lb & 7) * 144 + (lb >> 3);

    const int cg   = blk & 31;         // cout group (32 groups of 2)
    const int tile = (blk >> 5) % 9;   // 3x3 spatial tiles of 16x16
    const int b    = blk / 288;
    const int tx0 = (tile % 3) * 16, ty0 = (tile / 3) * 16;
    const int tid = threadIdx.x;
    const int tx = tid & 15, ty = tid >> 4;

    __shared__ float sl[2][18][20];

    float acc[2] = {0.f, 0.f};
    const float* wbase = w + cg * 2 * CIN * 9;

    // initial slice (cin = 0)
    {
        const float* ip = in + (b * CIN) * HW;
        for (int e = tid; e < 324; e += 256) {
            int ly = e / 18, lx = e % 18;
            int gy = ty0 + ly - 1, gx = tx0 + lx - 1;
            float v = 0.f;
            if (gy >= 0 && gy < 48 && gx >= 0 && gx < 48) v = ip[gy * 48 + gx];
            sl[0][ly][lx] = v;
        }
    }
    __syncthreads();

    for (int cin = 0; cin < CIN; ++cin) {
        if (cin + 1 < CIN) {  // prefetch next slice into the other buffer
            const float* ip = in + (b * CIN + cin + 1) * HW;
            int bufn = (cin + 1) & 1;
            for (int e = tid; e < 324; e += 256) {
                int ly = e / 18, lx = e % 18;
                int gy = ty0 + ly - 1, gx = tx0 + lx - 1;
                float v = 0.f;
                if (gy >= 0 && gy < 48 && gx >= 0 && gx < 48) v = ip[gy * 48 + gx];
                sl[bufn][ly][lx] = v;
            }
        }
        const int s = cin & 1;
        float xv[9];
#pragma unroll
        for (int dy = 0; dy < 3; dy++)
#pragma unroll
            for (int dx = 0; dx < 3; dx++) xv[dy * 3 + dx] = sl[s][ty + dy][tx + dx];

        const float* wc = wbase + cin * 9;
#pragma unroll
        for (int k = 0; k < 2; k++) {
            const float* wk = wc + k * CIN * 9;  // wave-uniform -> s_loads
            float a = acc[k];
#pragma unroll
            for (int d = 0; d < 9; d++) a = fmaf(wk[d], xv[d], a);
            acc[k] = a;
        }
        __syncthreads();
    }

    const int oy = ty0 + ty, ox = tx0 + tx;
#pragma unroll
    for (int k = 0; k < 2; k++) {
        int o = cg * 2 + k;
        float sc = bng[o] * rsqrtf(bnv[o] + 1e-5f);
        float sh = bnb[o] - bnm[o] * sc;
        float y = fmaf(acc[k] + bias[o], sc, sh);
        y = y > 0.f ? y : 0.01f * y;
        out[(b * 64 + o) * HW + oy * 48 + ox] = y;
    }
}

// ---------------------------------------------------------------------------
// Per-position value vectors (1x1 conv 64->8) and squared norms.
// d: [4][64][2304]  ->  vbuf[m][b][j][8], rbuf[m][b][j]
// Block: 256 thr = 64 j-positions x 4 c-quarters; shfl width-4 reduce.
// Grid: 3m * 4b * 36 jseg = 432.
// ---------------------------------------------------------------------------
__global__ __launch_bounds__(256) void value_r_kernel(
    const float* __restrict__ d1, const float* __restrict__ d2,
    const float* __restrict__ d3, const float* __restrict__ Wv,
    const float* __restrict__ bv, float* __restrict__ vbuf,
    float* __restrict__ rbuf) {
    __shared__ float sWv[512];
    int blk = blockIdx.x;
    int jseg = blk % 36;
    int b = (blk / 36) % 4;
    int m = blk / 144;
    int tid = threadIdx.x;
    sWv[tid] = Wv[tid];
    if (tid < 256) sWv[tid + 256] = Wv[tid + 256];
    __syncthreads();

    int jl = tid >> 2, cp = tid & 3;
    int j = jseg * 64 + jl;
    const float* dm = (m == 0) ? d1 : (m == 1) ? d2 : d3;
    const float* dp = dm + (b * 64) * HW + j;
    float acc[8];
#pragma unroll
    for (int k = 0; k < 8; k++) acc[k] = 0.f;
    float r = 0.f;
#pragma unroll 4
    for (int cc = 0; cc < 16; ++cc) {
        int c = cp * 16 + cc;
        float x = dp[c * HW];
        r = fmaf(x, x, r);
#pragma unroll
        for (int k = 0; k < 8; k++) acc[k] = fmaf(x, sWv[k * 64 + c], acc[k]);
    }
    r += __shfl_xor(r, 1, 4);
    r += __shfl_xor(r, 2, 4);
    float* vp = vbuf + ((m * 4 + b) * HW + j) * 8;
#pragma unroll
    for (int k = 0; k < 8; k++) {
        float v = acc[k];
        v += __shfl_xor(v, 1, 4);
        v += __shfl_xor(v, 2, 4);
        if (cp == 0) vp[k] = v + bv[k];
    }
    if (cp == 0) rbuf[(m * 4 + b) * HW + j] = r;
}

// ---------------------------------------------------------------------------
// Fused similarity-attention, j-split for occupancy.
// Grid: 4b * 72 i-tiles(32 rows) * 9 j-segments(256 cols) = 2592 blocks.
// Each block: Gram tiles on the fly -> exp -> 3 combos -> PV partials ->
// shfl-reduce over 16 tj lanes -> fp32 atomicAdd into attbuf (zeroed before).
// ---------------------------------------------------------------------------
__global__ __launch_bounds__(256) void attn_kernel(
    const float* __restrict__ d1, const float* __restrict__ d2,
    const float* __restrict__ d3, const float* __restrict__ vbuf,
    const float* __restrict__ rbuf, const float* __restrict__ gam,
    float* __restrict__ attbuf) {
    // bijective XCD swizzle: 2592 % 8 == 0, chunk 324, b-major ->
    // each XCD works within one batch (1.77 MB d-set fits 4 MB XCD L2).
    int lb = blockIdx.x;
    int blk = (lb & 7) * 324 + (lb >> 3);
    const int js = blk % 9;
    const int it = (blk / 9) % 72;
    const int b  = blk / 648;
    const int i0 = it * 32;
    const int tid = threadIdx.x;
    const int tj = tid & 15;
    const int ti = tid >> 4;

    __shared__ float Fi[3][64][32];
    __shared__ float Ri[3][32];

    for (int e = tid; e < 3 * 64 * 32; e += 256) {
        int m = e >> 11;
        int c = (e >> 5) & 63;
        int i = e & 31;
        const float* dm = (m == 0) ? d1 : (m == 1) ? d2 : d3;
        Fi[m][c][i] = dm[(b * 64 + c) * HW + i0 + i];
    }
    if (tid < 96) {
        int m = tid >> 5, i = tid & 31;
        Ri[m][i] = rbuf[(m * 4 + b) * HW + i0 + i];
    }

    float g0 = gam[0], g1 = gam[1], g2 = gam[2];
    float inv0 = 1.f / (2.f * g0 * g0);
    float inv1 = 1.f / (2.f * g1 * g1);
    float inv2 = 1.f / (2.f * g2 * g2);
    float g6 = gam[6], g7 = gam[7], g8 = gam[8];
    float c00 = g6,       c01 = g7 + 1.f, c02 = g8 + 1.f;
    float c10 = g6 + 1.f, c11 = g7,       c12 = g8 + 1.f;
    float c20 = g6 + 1.f, c21 = g7 + 1.f, c22 = g8;

    __syncthreads();

    float ri0[2], ri1[2], ri2[2];
    ri0[0] = Ri[0][2 * ti]; ri0[1] = Ri[0][2 * ti + 1];
    ri1[0] = Ri[1][2 * ti]; ri1[1] = Ri[1][2 * ti + 1];
    ri2[0] = Ri[2][2 * ti]; ri2[1] = Ri[2][2 * ti + 1];

    float pv[3][2][8];
#pragma unroll
    for (int m = 0; m < 3; m++)
#pragma unroll
        for (int r = 0; r < 2; r++)
#pragma unroll
            for (int k = 0; k < 8; k++) pv[m][r][k] = 0.f;

    const float* q0 = d1 + (b * 64) * HW + 4 * tj;
    const float* q1 = d2 + (b * 64) * HW + 4 * tj;
    const float* q2 = d3 + (b * 64) * HW + 4 * tj;
    const float* rb0 = rbuf + (0 * 4 + b) * HW + 4 * tj;
    const float* rb1 = rbuf + (1 * 4 + b) * HW + 4 * tj;
    const float* rb2 = rbuf + (2 * 4 + b) * HW + 4 * tj;

    for (int jj = 0; jj < 4; ++jj) {
        const int j0 = (js * 4 + jj) * 64;
        float fa0[2][4], fa1[2][4], fa2[2][4];
#pragma unroll
        for (int r = 0; r < 2; r++)
#pragma unroll
            for (int q = 0; q < 4; q++) { fa0[r][q] = 0.f; fa1[r][q] = 0.f; fa2[r][q] = 0.f; }

#pragma unroll 2
        for (int c = 0; c < 64; ++c) {
            const float2 fi0 = *(const float2*)&Fi[0][c][2 * ti];
            const float2 fi1 = *(const float2*)&Fi[1][c][2 * ti];
            const float2 fi2 = *(const float2*)&Fi[2][c][2 * ti];
            float4 fj0 = *(const float4*)(q0 + c * HW + j0);
            float4 fj1 = *(const float4*)(q1 + c * HW + j0);
            float4 fj2 = *(const float4*)(q2 + c * HW + j0);
            float a0[4] = {fj0.x, fj0.y, fj0.z, fj0.w};
            float a1[4] = {fj1.x, fj1.y, fj1.z, fj1.w};
            float a2[4] = {fj2.x, fj2.y, fj2.z, fj2.w};
#pragma unroll
            for (int q = 0; q < 4; q++) {
                fa0[0][q] = fmaf(fi0.x, a0[q], fa0[0][q]);
                fa0[1][q] = fmaf(fi0.y, a0[q], fa0[1][q]);
                fa1[0][q] = fmaf(fi1.x, a1[q], fa1[0][q]);
                fa1[1][q] = fmaf(fi1.y, a1[q], fa1[1][q]);
                fa2[0][q] = fmaf(fi2.x, a2[q], fa2[0][q]);
                fa2[1][q] = fmaf(fi2.y, a2[q], fa2[1][q]);
            }
        }

        float4 rj0 = *(const float4*)(rb0 + j0);
        float4 rj1 = *(const float4*)(rb1 + j0);
        float4 rj2 = *(const float4*)(rb2 + j0);
        float rj0a[4] = {rj0.x, rj0.y, rj0.z, rj0.w};
        float rj1a[4] = {rj1.x, rj1.y, rj1.z, rj1.w};
        float rj2a[4] = {rj2.x, rj2.y, rj2.z, rj2.w};

#pragma unroll
        for (int q = 0; q < 4; q++) {
            const int j = j0 + 4 * tj + q;
            const float* vp0 = vbuf + ((0 * 4 + b) * HW + j) * 8;
            const float* vp1 = vbuf + ((1 * 4 + b) * HW + j) * 8;
            const float* vp2 = vbuf + ((2 * 4 + b) * HW + j) * 8;
            float4 v0a = *(const float4*)vp0, v0b = *(const float4*)(vp0 + 4);
            float4 v1a = *(const float4*)vp1, v1b = *(const float4*)(vp1 + 4);
            float4 v2a = *(const float4*)vp2, v2b = *(const float4*)(vp2 + 4);
            float v0[8] = {v0a.x, v0a.y, v0a.z, v0a.w, v0b.x, v0b.y, v0b.z, v0b.w};
            float v1[8] = {v1a.x, v1a.y, v1a.z, v1a.w, v1b.x, v1b.y, v1b.z, v1b.w};
            float v2[8] = {v2a.x, v2a.y, v2a.z, v2a.w, v2b.x, v2b.y, v2b.z, v2b.w};
#pragma unroll
            for (int r = 0; r < 2; r++) {
                float t0 = fmaxf(ri0[r] + rj0a[q] - 2.f * fa0[r][q], 0.f);
                float t1 = fmaxf(ri1[r] + rj1a[q] - 2.f * fa1[r][q], 0.f);
                float t2 = fmaxf(ri2[r] + rj2a[q] - 2.f * fa2[r][q], 0.f);
                float a0e = __expf(-t0 * inv0);
                float a1e = __expf(-t1 * inv1);
                float a2e = __expf(-t2 * inv2);
                float u0 = c00 * a0e + c01 * a1e + c02 * a2e;
                float u1 = c10 * a0e + c11 * a1e + c12 * a2e;
                float u2 = c20 * a0e + c21 * a1e + c22 * a2e;
#pragma unroll
                for (int k = 0; k < 8; k++) {
                    pv[0][r][k] = fmaf(u0, v0[k], pv[0][r][k]);
                    pv[1][r][k] = fmaf(u1, v1[k], pv[1][r][k]);
                    pv[2][r][k] = fmaf(u2, v2[k], pv[2][r][k]);
                }
            }
        }
    }

    // reduce across the 16 tj lanes, then atomically accumulate the j-segment
    // partial into attbuf (linear in gs, so scaling before the add is fine).
    float gs0 = gam[3], gs1 = gam[4], gs2 = gam[5];
#pragma unroll
    for (int m = 0; m < 3; m++) {
        float gs = (m == 0) ? gs0 : (m == 1) ? gs1 : gs2;
#pragma unroll
        for (int r = 0; r < 2; r++)
#pragma unroll
            for (int k = 0; k < 8; k++) {
                float v = pv[m][r][k] * gs;
                v += __shfl_xor(v, 1, 16);
                v += __shfl_xor(v, 2, 16);
                v += __shfl_xor(v, 4, 16);
                v += __shfl_xor(v, 8, 16);
                if (tj == 0)
                    atomicAdd(&attbuf[((m * 4 + b) * HW + i0 + 2 * ti + r) * 8 + k], v);
            }
    }
}

// ---------------------------------------------------------------------------
// out[m][b][c][j] = d_m[b][c][j] * (att_m[b][j][:] . Wo[c][:] + bo[c]) + edge[b][j]
// ---------------------------------------------------------------------------
__global__ __launch_bounds__(256) void final_kernel(
    const float* __restrict__ d1, const float* __restrict__ d2,
    const float* __restrict__ d3, const float* __restrict__ attbuf,
    const float* __restrict__ Wo, const float* __restrict__ bo,
    const float* __restrict__ edge, float* __restrict__ out) {
    int blk = blockIdx.x;  // 3*4*64*9 = 6912
    int jt = blk % 9;
    int c = (blk / 9) % 64;
    int b = (blk / (9 * 64)) % 4;
    int m = blk / (9 * 64 * 4);
    int j = jt * 256 + threadIdx.x;
    const float* dm = (m == 0) ? d1 : (m == 1) ? d2 : d3;
    const float* ap = attbuf + ((m * 4 + b) * HW + j) * 8;
    float4 aa = *(const float4*)ap, ab = *(const float4*)(ap + 4);
    float av[8] = {aa.x, aa.y, aa.z, aa.w, ab.x, ab.y, ab.z, ab.w};
    float s = bo[c];
#pragma unroll
    for (int k = 0; k < 8; k++) s = fmaf(av[k], Wo[c * 8 + k], s);
    float val = fmaf(dm[(b * 64 + c) * HW + j], s, edge[b * HW + j]);
    out[((m * 4 + b) * 64 + c) * HW + j] = val;
}

// ---------------------------------------------------------------------------
extern "C" void kernel_launch(void* const* d_in, const int* in_sizes, int n_in,
                              void* d_out, int out_size, void* d_ws, size_t ws_size,
                              hipStream_t stream) {
    (void)in_sizes; (void)n_in; (void)out_size; (void)ws_size;
    const float* x1   = (const float*)d_in[0];
    const float* x2   = (const float*)d_in[1];
    const float* x3   = (const float*)d_in[2];
    const float* Wc1  = (const float*)d_in[3];
    const float* bc1  = (const float*)d_in[4];
    const float* Wc2  = (const float*)d_in[5];
    const float* bc2  = (const float*)d_in[6];
    const float* Wc3  = (const float*)d_in[7];
    const float* bc3  = (const float*)d_in[8];
    const float* bnf_g = (const float*)d_in[9];
    const float* bnf_b = (const float*)d_in[10];
    const float* bnf_m = (const float*)d_in[11];
    const float* bnf_v = (const float*)d_in[12];
    const float* Wm   = (const float*)d_in[13];
    const float* bm   = (const float*)d_in[14];
    const float* bnm_g = (const float*)d_in[15];
    const float* bnm_b = (const float*)d_in[16];
    const float* bnm_m = (const float*)d_in[17];
    const float* bnm_v = (const float*)d_in[18];
    const float* Wv   = (const float*)d_in[19];
    const float* bv   = (const float*)d_in[20];
    const float* Wo   = (const float*)d_in[21];
    const float* bo   = (const float*)d_in[22];
    const float* gam  = (const float*)d_in[23];

    float* ws = (float*)d_ws;
    const int NB = 4 * 64 * HW;  // 589824 floats per activation buffer
    float* A1 = ws;
    float* A2 = A1 + NB;
    float* B1 = A2 + NB;
    float* B2 = B1 + NB;
    float* C1 = B2 + NB;
    float* C2 = C1 + NB;
    float* edge = C2 + NB;               // 4*2304
    float* vbuf = edge + 4 * HW;         // 3*4*2304*8
    float* rbuf = vbuf + 3 * 4 * HW * 8; // 3*4*2304
    float* attb = rbuf + 3 * 4 * HW;     // 3*4*2304*8

    const int WMS = 64 * 64 * 9;  // Wm per-conv stride

    edge_kernel<<<36, 256, 0, stream>>>(x3, edge);
    // zero the attention accumulator (attn_kernel atomically adds partials)
    zero_kernel<<<216, 256, 0, stream>>>((float4*)attb);

    conv_bn_lrelu<144><<<1152, 256, 0, stream>>>(x1, Wc1, bc1, bnf_g, bnf_b, bnf_m, bnf_v, A1);
    conv_bn_lrelu<21><<<1152, 256, 0, stream>>>(x2, Wc2, bc2, bnf_g + 64, bnf_b + 64, bnf_m + 64, bnf_v + 64, B1);
    conv_bn_lrelu<1><<<1152, 256, 0, stream>>>(x3, Wc3, bc3, bnf_g + 128, bnf_b + 128, bnf_m + 128, bnf_v + 128, C1);

    conv_bn_lrelu<64><<<1152, 256, 0, stream>>>(A1, Wm + 0 * WMS, bm + 0,   bnm_g + 0,   bnm_b + 0,   bnm_m + 0,   bnm_v + 0,   A2);
    conv_bn_lrelu<64><<<1152, 256, 0, stream>>>(A2, Wm + 1 * WMS, bm + 64,  bnm_g + 64,  bnm_b + 64,  bnm_m + 64,  bnm_v + 64,  A1);
    conv_bn_lrelu<64><<<1152, 256, 0, stream>>>(B1, Wm + 2 * WMS, bm + 128, bnm_g + 128, bnm_b + 128, bnm_m + 128, bnm_v + 128, B2);
    conv_bn_lrelu<64><<<1152, 256, 0, stream>>>(B2, Wm + 3 * WMS, bm + 192, bnm_g + 192, bnm_b + 192, bnm_m + 192, bnm_v + 192, B1);
    conv_bn_lrelu<64><<<1152, 256, 0, stream>>>(C1, Wm + 4 * WMS, bm + 256, bnm_g + 256, bnm_b + 256, bnm_m + 256, bnm_v + 256, C2);
    conv_bn_lrelu<64><<<1152, 256, 0, stream>>>(C2, Wm + 5 * WMS, bm + 320, bnm_g + 320, bnm_b + 320, bnm_m + 320, bnm_v + 320, C1);

    value_r_kernel<<<432, 256, 0, stream>>>(A1, B1, C1, Wv, bv, vbuf, rbuf);
    attn_kernel<<<2592, 256, 0, stream>>>(A1, B1, C1, vbuf, rbuf, gam, attb);
    final_kernel<<<6912, 256, 0, stream>>>(A1, B1, C1, attb, Wo, bo, edge, (float*)d_out);
}

// Round 5
// 952.003 us; speedup vs baseline: 1.3399x; 1.0748x over previous
//
#include <hip/hip_runtime.h>

#define HW 2304   // 48*48

// ---------------------------------------------------------------------------
// Zero the attention accumulator (attn_kernel atomically adds partials).
// ---------------------------------------------------------------------------
__global__ __launch_bounds__(256) void zero_kernel(float4* __restrict__ p) {
    p[blockIdx.x * 256 + threadIdx.x] = make_float4(0.f, 0.f, 0.f, 0.f);
}

// ---------------------------------------------------------------------------
// Sobel edge magnitude on x3 (C=1), SAME zero padding.  [4,48,48] -> [4,2304]
// ---------------------------------------------------------------------------
__global__ __launch_bounds__(256) void edge_kernel(const float* __restrict__ x3,
                                                   float* __restrict__ edge) {
    int idx = blockIdx.x * 256 + threadIdx.x;   // < 9216
    int b = idx / HW;
    int j = idx % HW;
    int y = j / 48, x = j % 48;
    const float* p = x3 + b * HW;
    auto at = [&](int yy, int xx) -> float {
        return (yy >= 0 && yy < 48 && xx >= 0 && xx < 48) ? p[yy * 48 + xx] : 0.f;
    };
    float a00 = at(y - 1, x - 1), a01 = at(y - 1, x), a02 = at(y - 1, x + 1);
    float a10 = at(y, x - 1),                         a12 = at(y, x + 1);
    float a20 = at(y + 1, x - 1), a21 = at(y + 1, x), a22 = at(y + 1, x + 1);
    float ex = (a02 - a00) + 2.f * (a12 - a10) + (a22 - a20);
    float ey = (a20 - a00) + 2.f * (a21 - a01) + (a22 - a02);
    edge[idx] = sqrtf(ex * ex + ey * ey);
}

// ---------------------------------------------------------------------------
// conv3x3 + BN(eval) + LeakyReLU body.  16x16 spatial tile, NC=2 couts/block.
// Staging: per-thread (goff,loff,cl) slots precomputed ONCE (cin-invariant);
// 8 cins staged per barrier, double-buffered LDS [2][8][18][20].
// ---------------------------------------------------------------------------
template <int CIN>
__device__ __forceinline__ void conv_body(
    const float* __restrict__ in, const float* __restrict__ w,
    const float* __restrict__ bias,
    const float* __restrict__ bng, const float* __restrict__ bnb,
    const float* __restrict__ bnm, const float* __restrict__ bnv,
    float* __restrict__ out, int cg, int tile, int b) {
    const int tx0 = (tile % 3) * 16, ty0 = (tile / 3) * 16;
    const int tid = threadIdx.x;
    const int tx = tid & 15, ty = tid >> 4;

    __shared__ float sl[2][2880];   // [buf][8 cin][18][20]

    // per-thread staging slots (cin-chunk invariant): e = tid + t*256 < 2592
    int goff[11], loff[11], clv[11];
#pragma unroll
    for (int t = 0; t < 11; ++t) {
        int e = tid + t * 256;
        int cl = e / 324; int r = e - cl * 324;
        int ly = r / 18;  int lx = r - ly * 18;
        int gy = ty0 + ly - 1, gx = tx0 + lx - 1;
        bool live = (e < 2592);
        bool inb = live && gy >= 0 && gy < 48 && gx >= 0 && gx < 48;
        goff[t] = inb ? (gy * 48 + gx) : -1;
        loff[t] = live ? (cl * 360 + ly * 20 + lx) : -1;
        clv[t] = cl;
    }

    auto stage = [&](int c0, int bf) {
#pragma unroll
        for (int t = 0; t < 11; ++t) {
            if (loff[t] >= 0) {
                int cin = c0 + clv[t];
                float v = 0.f;
                if (goff[t] >= 0 && (CIN % 8 == 0 || cin < CIN))
                    v = in[(b * CIN + cin) * HW + goff[t]];
                sl[bf][loff[t]] = v;
            }
        }
    };

    float acc[2] = {0.f, 0.f};

    auto compute = [&](int c0, int bf) {
#pragma unroll
        for (int cl = 0; cl < 8; ++cl) {
            if (CIN % 8 != 0 && c0 + cl >= CIN) continue;
            float xv[9];
#pragma unroll
            for (int dy = 0; dy < 3; dy++)
#pragma unroll
                for (int dx = 0; dx < 3; dx++)
                    xv[dy * 3 + dx] = sl[bf][cl * 360 + (ty + dy) * 20 + (tx + dx)];
#pragma unroll
            for (int k = 0; k < 2; ++k) {
                const float* wk = w + ((cg * 2 + k) * CIN + (c0 + cl)) * 9;  // wave-uniform
                float a = acc[k];
#pragma unroll
                for (int d = 0; d < 9; ++d) a = fmaf(wk[d], xv[d], a);
                acc[k] = a;
            }
        }
    };

    constexpr int NCH = (CIN + 7) / 8;
    stage(0, 0);
    __syncthreads();
#pragma unroll 1
    for (int ch = 0; ch < NCH; ++ch) {
        if (ch + 1 < NCH) stage((ch + 1) * 8, (ch + 1) & 1);
        compute(ch * 8, ch & 1);
        __syncthreads();
    }

    const int oy = ty0 + ty, ox = tx0 + tx;
#pragma unroll
    for (int k = 0; k < 2; ++k) {
        int o = cg * 2 + k;
        float sc = bng[o] * rsqrtf(bnv[o] + 1e-5f);
        float sh = bnb[o] - bnm[o] * sc;
        float y = fmaf(acc[k] + bias[o], sc, sh);
        y = y > 0.f ? y : 0.01f * y;
        out[(b * 64 + o) * HW + oy * 48 + ox] = y;
    }
}

// First-layer convs: grid 1152 = 4b * 9 tiles * 32 cout-groups, XCD-swizzled.
template <int CIN>
__global__ __launch_bounds__(256) void conv_first(
    const float* __restrict__ in, const float* __restrict__ w,
    const float* __restrict__ bias,
    const float* __restrict__ bng, const float* __restrict__ bnb,
    const float* __restrict__ bnm, const float* __restrict__ bnv,
    float* __restrict__ out) {
    int lb = blockIdx.x;
    int blk = (lb & 7) * 144 + (lb >> 3);
    int cg = blk & 31, tile = (blk >> 5) % 9, b = blk / 288;
    conv_body<CIN>(in, w, bias, bng, bnb, bnm, bnv, out, cg, tile, b);
}

// Fused 64->64 convs for the three branches (step 0: Wm slots {0,2,4};
// step 1: slots {1,3,5}).  Grid 3456 = 3 branches * 1152.
__global__ __launch_bounds__(256) void conv64_3(
    const float* __restrict__ inA, const float* __restrict__ inB,
    const float* __restrict__ inC, float* __restrict__ outA,
    float* __restrict__ outB, float* __restrict__ outC,
    const float* __restrict__ Wm, const float* __restrict__ bm,
    const float* __restrict__ bng, const float* __restrict__ bnb,
    const float* __restrict__ bnm, const float* __restrict__ bnv, int step) {
    int lb = blockIdx.x;
    int blk = (lb & 7) * 432 + (lb >> 3);
    int br = blk / 1152;
    int rr = blk - br * 1152;
    int cg = rr & 31, tile = (rr >> 5) % 9, b = rr / 288;
    const float* in = (br == 0) ? inA : (br == 1) ? inB : inC;
    float* out = (br == 0) ? outA : (br == 1) ? outB : outC;
    int so = 2 * br + step;
    conv_body<64>(in, Wm + so * (64 * 64 * 9), bm + so * 64,
                  bng + so * 64, bnb + so * 64, bnm + so * 64, bnv + so * 64,
                  out, cg, tile, b);
}

// ---------------------------------------------------------------------------
// Per-position value vectors (1x1 conv 64->8) and squared norms.
// ---------------------------------------------------------------------------
__global__ __launch_bounds__(256) void value_r_kernel(
    const float* __restrict__ d1, const float* __restrict__ d2,
    const float* __restrict__ d3, const float* __restrict__ Wv,
    const float* __restrict__ bv, float* __restrict__ vbuf,
    float* __restrict__ rbuf) {
    __shared__ float sWv[512];
    int blk = blockIdx.x;
    int jseg = blk % 36;
    int b = (blk / 36) % 4;
    int m = blk / 144;
    int tid = threadIdx.x;
    sWv[tid] = Wv[tid];
    if (tid < 256) sWv[tid + 256] = Wv[tid + 256];
    __syncthreads();

    int jl = tid >> 2, cp = tid & 3;
    int j = jseg * 64 + jl;
    const float* dm = (m == 0) ? d1 : (m == 1) ? d2 : d3;
    const float* dp = dm + (b * 64) * HW + j;
    float acc[8];
#pragma unroll
    for (int k = 0; k < 8; k++) acc[k] = 0.f;
    float r = 0.f;
#pragma unroll 4
    for (int cc = 0; cc < 16; ++cc) {
        int c = cp * 16 + cc;
        float x = dp[c * HW];
        r = fmaf(x, x, r);
#pragma unroll
        for (int k = 0; k < 8; k++) acc[k] = fmaf(x, sWv[k * 64 + c], acc[k]);
    }
    r += __shfl_xor(r, 1, 4);
    r += __shfl_xor(r, 2, 4);
    float* vp = vbuf + ((m * 4 + b) * HW + j) * 8;
#pragma unroll
    for (int k = 0; k < 8; k++) {
        float v = acc[k];
        v += __shfl_xor(v, 1, 4);
        v += __shfl_xor(v, 2, 4);
        if (cp == 0) vp[k] = v + bv[k];
    }
    if (cp == 0) rbuf[(m * 4 + b) * HW + j] = r;
}

// ---------------------------------------------------------------------------
// Fused similarity-attention v3: LDS-tiled Gram + PV.
// Grid 2592 = 4b * 72 i-tiles(32) * 9 j-segments(256).  Per j-subtile (64):
//   Fj[3][64][64] + V-tile staged in LDS (reg-staged, issue-early/write-late);
//   Gram from LDS (ds_read_b128/b64, conflict-free) -> exp -> combos -> PV.
// LDS 78 KB -> 2 blocks/CU; atomics into attbuf as partials.
// ---------------------------------------------------------------------------
__global__ __launch_bounds__(256, 2) void attn_kernel(
    const float* __restrict__ d1, const float* __restrict__ d2,
    const float* __restrict__ d3, const float* __restrict__ vbuf,
    const float* __restrict__ rbuf, const float* __restrict__ gam,
    float* __restrict__ attbuf) {
    int lb = blockIdx.x;
    int blk = (lb & 7) * 324 + (lb >> 3);
    const int js = blk % 9;
    const int it = (blk / 9) % 72;
    const int b  = blk / 648;
    const int i0 = it * 32;
    const int tid = threadIdx.x;
    const int tj = tid & 15;
    const int ti = tid >> 4;

    __shared__ float Fi[3 * 64 * 32];      // [m][c][i]      24576 B
    __shared__ float Fj[3 * 64 * 64];      // [m][c][j]      49152 B
    __shared__ float Vj[2 * 3 * 64 * 4];   // [half][m][j][4] 6144 B

    // ---- stage Fi (once): 1536 float4 ----
#pragma unroll
    for (int t = 0; t < 6; ++t) {
        int idx = t * 256 + tid;
        int col4 = idx & 7, row = idx >> 3;
        int c = row & 63, m = row >> 6;
        const float* dm = (m == 0) ? d1 : (m == 1) ? d2 : d3;
        *(float4*)&Fi[idx * 4] =
            *(const float4*)(dm + (b * 64 + c) * HW + i0 + col4 * 4);
    }

    float g0 = gam[0], g1 = gam[1], g2 = gam[2];
    float inv0 = 1.f / (2.f * g0 * g0);
    float inv1 = 1.f / (2.f * g1 * g1);
    float inv2 = 1.f / (2.f * g2 * g2);
    float g6 = gam[6], g7 = gam[7], g8 = gam[8];
    float c00 = g6,       c01 = g7 + 1.f, c02 = g8 + 1.f;
    float c10 = g6 + 1.f, c11 = g7,       c12 = g8 + 1.f;
    float c20 = g6 + 1.f, c21 = g7 + 1.f, c22 = g8;

    float ri0[2], ri1[2], ri2[2];
    ri0[0] = rbuf[(0 * 4 + b) * HW + i0 + 2 * ti]; ri0[1] = rbuf[(0 * 4 + b) * HW + i0 + 2 * ti + 1];
    ri1[0] = rbuf[(1 * 4 + b) * HW + i0 + 2 * ti]; ri1[1] = rbuf[(1 * 4 + b) * HW + i0 + 2 * ti + 1];
    ri2[0] = rbuf[(2 * 4 + b) * HW + i0 + 2 * ti]; ri2[1] = rbuf[(2 * 4 + b) * HW + i0 + 2 * ti + 1];

    float pv[3][2][8];
#pragma unroll
    for (int m = 0; m < 3; m++)
#pragma unroll
        for (int r = 0; r < 2; r++)
#pragma unroll
            for (int k = 0; k < 8; k++) pv[m][r][k] = 0.f;

    // register-staged tile loaders (T14: issue-early / write-late)
    float4 fjreg[12], vjA, vjB;
    auto load_tile = [&](int j0) {
#pragma unroll
        for (int t = 0; t < 12; ++t) {
            int idx = t * 256 + tid;
            int col4 = idx & 15, row = idx >> 4;
            int c = row & 63, m = row >> 6;
            const float* dm = (m == 0) ? d1 : (m == 1) ? d2 : d3;
            fjreg[t] = *(const float4*)(dm + (b * 64 + c) * HW + j0 + col4 * 4);
        }
        if (tid < 192) {
            int m = tid >> 6, jl = tid & 63;
            const float* vp = vbuf + ((m * 4 + b) * HW + j0 + jl) * 8;
            vjA = *(const float4*)vp;
            vjB = *(const float4*)(vp + 4);
        }
    };
    auto write_tile = [&]() {
#pragma unroll
        for (int t = 0; t < 12; ++t) {
            int idx = t * 256 + tid;
            *(float4*)&Fj[idx * 4] = fjreg[t];
        }
        if (tid < 192) {
            int m = tid >> 6, jl = tid & 63;
            *(float4*)&Vj[((0 * 3 + m) * 64 + jl) * 4] = vjA;
            *(float4*)&Vj[((1 * 3 + m) * 64 + jl) * 4] = vjB;
        }
    };

    load_tile(js * 256);
    write_tile();
    __syncthreads();   // also covers Fi

#pragma unroll 1
    for (int jj = 0; jj < 4; ++jj) {
        const int j0 = (js * 4 + jj) * 64;
        if (jj < 3) load_tile(j0 + 64);   // issue next tile early

        float fa0[2][4], fa1[2][4], fa2[2][4];
#pragma unroll
        for (int r = 0; r < 2; r++)
#pragma unroll
            for (int q = 0; q < 4; q++) { fa0[r][q] = 0.f; fa1[r][q] = 0.f; fa2[r][q] = 0.f; }

#pragma unroll 4
        for (int c = 0; c < 64; ++c) {
            float4 fj0 = *(const float4*)&Fj[(0 * 64 + c) * 64 + 4 * tj];
            float4 fj1 = *(const float4*)&Fj[(1 * 64 + c) * 64 + 4 * tj];
            float4 fj2 = *(const float4*)&Fj[(2 * 64 + c) * 64 + 4 * tj];
            float2 fi0 = *(const float2*)&Fi[(0 * 64 + c) * 32 + 2 * ti];
            float2 fi1 = *(const float2*)&Fi[(1 * 64 + c) * 32 + 2 * ti];
            float2 fi2 = *(const float2*)&Fi[(2 * 64 + c) * 32 + 2 * ti];
            float a0[4] = {fj0.x, fj0.y, fj0.z, fj0.w};
            float a1[4] = {fj1.x, fj1.y, fj1.z, fj1.w};
            float a2[4] = {fj2.x, fj2.y, fj2.z, fj2.w};
#pragma unroll
            for (int q = 0; q < 4; q++) {
                fa0[0][q] = fmaf(fi0.x, a0[q], fa0[0][q]);
                fa0[1][q] = fmaf(fi0.y, a0[q], fa0[1][q]);
                fa1[0][q] = fmaf(fi1.x, a1[q], fa1[0][q]);
                fa1[1][q] = fmaf(fi1.y, a1[q], fa1[1][q]);
                fa2[0][q] = fmaf(fi2.x, a2[q], fa2[0][q]);
                fa2[1][q] = fmaf(fi2.y, a2[q], fa2[1][q]);
            }
        }

        float4 rj0 = *(const float4*)(rbuf + (0 * 4 + b) * HW + j0 + 4 * tj);
        float4 rj1 = *(const float4*)(rbuf + (1 * 4 + b) * HW + j0 + 4 * tj);
        float4 rj2 = *(const float4*)(rbuf + (2 * 4 + b) * HW + j0 + 4 * tj);
        float rj0a[4] = {rj0.x, rj0.y, rj0.z, rj0.w};
        float rj1a[4] = {rj1.x, rj1.y, rj1.z, rj1.w};
        float rj2a[4] = {rj2.x, rj2.y, rj2.z, rj2.w};

#pragma unroll
        for (int q = 0; q < 4; ++q) {
            const int jl = 4 * tj + q;
            float4 v0a = *(const float4*)&Vj[((0 * 3 + 0) * 64 + jl) * 4];
            float4 v0b = *(const float4*)&Vj[((1 * 3 + 0) * 64 + jl) * 4];
            float4 v1a = *(const float4*)&Vj[((0 * 3 + 1) * 64 + jl) * 4];
            float4 v1b = *(const float4*)&Vj[((1 * 3 + 1) * 64 + jl) * 4];
            float4 v2a = *(const float4*)&Vj[((0 * 3 + 2) * 64 + jl) * 4];
            float4 v2b = *(const float4*)&Vj[((1 * 3 + 2) * 64 + jl) * 4];
            float v0[8] = {v0a.x, v0a.y, v0a.z, v0a.w, v0b.x, v0b.y, v0b.z, v0b.w};
            float v1[8] = {v1a.x, v1a.y, v1a.z, v1a.w, v1b.x, v1b.y, v1b.z, v1b.w};
            float v2[8] = {v2a.x, v2a.y, v2a.z, v2a.w, v2b.x, v2b.y, v2b.z, v2b.w};
#pragma unroll
            for (int r = 0; r < 2; ++r) {
                float t0 = fmaxf(ri0[r] + rj0a[q] - 2.f * fa0[r][q], 0.f);
                float t1 = fmaxf(ri1[r] + rj1a[q] - 2.f * fa1[r][q], 0.f);
                float t2 = fmaxf(ri2[r] + rj2a[q] - 2.f * fa2[r][q], 0.f);
                float a0e = __expf(-t0 * inv0);
                float a1e = __expf(-t1 * inv1);
                float a2e = __expf(-t2 * inv2);
                float u0 = c00 * a0e + c01 * a1e + c02 * a2e;
                float u1 = c10 * a0e + c11 * a1e + c12 * a2e;
                float u2 = c20 * a0e + c21 * a1e + c22 * a2e;
#pragma unroll
                for (int k = 0; k < 8; k++) {
                    pv[0][r][k] = fmaf(u0, v0[k], pv[0][r][k]);
                    pv[1][r][k] = fmaf(u1, v1[k], pv[1][r][k]);
                    pv[2][r][k] = fmaf(u2, v2[k], pv[2][r][k]);
                }
            }
        }

        __syncthreads();               // compute-reads done
        if (jj < 3) write_tile();      // write next tile (loads have landed)
        __syncthreads();               // tile ready
    }

    float gs0 = gam[3], gs1 = gam[4], gs2 = gam[5];
#pragma unroll
    for (int m = 0; m < 3; m++) {
        float gs = (m == 0) ? gs0 : (m == 1) ? gs1 : gs2;
#pragma unroll
        for (int r = 0; r < 2; r++)
#pragma unroll
            for (int k = 0; k < 8; k++) {
                float v = pv[m][r][k] * gs;
                v += __shfl_xor(v, 1, 16);
                v += __shfl_xor(v, 2, 16);
                v += __shfl_xor(v, 4, 16);
                v += __shfl_xor(v, 8, 16);
                if (tj == 0)
                    atomicAdd(&attbuf[((m * 4 + b) * HW + i0 + 2 * ti + r) * 8 + k], v);
            }
    }
}

// ---------------------------------------------------------------------------
// out[m][b][c][j] = d_m[b][c][j] * (att_m[b][j][:] . Wo[c][:] + bo[c]) + edge[b][j]
// ---------------------------------------------------------------------------
__global__ __launch_bounds__(256) void final_kernel(
    const float* __restrict__ d1, const float* __restrict__ d2,
    const float* __restrict__ d3, const float* __restrict__ attbuf,
    const float* __restrict__ Wo, const float* __restrict__ bo,
    const float* __restrict__ edge, float* __restrict__ out) {
    int blk = blockIdx.x;  // 3*4*64*9 = 6912
    int jt = blk % 9;
    int c = (blk / 9) % 64;
    int b = (blk / (9 * 64)) % 4;
    int m = blk / (9 * 64 * 4);
    int j = jt * 256 + threadIdx.x;
    const float* dm = (m == 0) ? d1 : (m == 1) ? d2 : d3;
    const float* ap = attbuf + ((m * 4 + b) * HW + j) * 8;
    float4 aa = *(const float4*)ap, ab = *(const float4*)(ap + 4);
    float av[8] = {aa.x, aa.y, aa.z, aa.w, ab.x, ab.y, ab.z, ab.w};
    float s = bo[c];
#pragma unroll
    for (int k = 0; k < 8; k++) s = fmaf(av[k], Wo[c * 8 + k], s);
    float val = fmaf(dm[(b * 64 + c) * HW + j], s, edge[b * HW + j]);
    out[((m * 4 + b) * 64 + c) * HW + j] = val;
}

// ---------------------------------------------------------------------------
extern "C" void kernel_launch(void* const* d_in, const int* in_sizes, int n_in,
                              void* d_out, int out_size, void* d_ws, size_t ws_size,
                              hipStream_t stream) {
    (void)in_sizes; (void)n_in; (void)out_size; (void)ws_size;
    const float* x1   = (const float*)d_in[0];
    const float* x2   = (const float*)d_in[1];
    const float* x3   = (const float*)d_in[2];
    const float* Wc1  = (const float*)d_in[3];
    const float* bc1  = (const float*)d_in[4];
    const float* Wc2  = (const float*)d_in[5];
    const float* bc2  = (const float*)d_in[6];
    const float* Wc3  = (const float*)d_in[7];
    const float* bc3  = (const float*)d_in[8];
    const float* bnf_g = (const float*)d_in[9];
    const float* bnf_b = (const float*)d_in[10];
    const float* bnf_m = (const float*)d_in[11];
    const float* bnf_v = (const float*)d_in[12];
    const float* Wm   = (const float*)d_in[13];
    const float* bm   = (const float*)d_in[14];
    const float* bnm_g = (const float*)d_in[15];
    const float* bnm_b = (const float*)d_in[16];
    const float* bnm_m = (const float*)d_in[17];
    const float* bnm_v = (const float*)d_in[18];
    const float* Wv   = (const float*)d_in[19];
    const float* bv   = (const float*)d_in[20];
    const float* Wo   = (const float*)d_in[21];
    const float* bo   = (const float*)d_in[22];
    const float* gam  = (const float*)d_in[23];

    float* ws = (float*)d_ws;
    const int NB = 4 * 64 * HW;
    float* A1 = ws;
    float* A2 = A1 + NB;
    float* B1 = A2 + NB;
    float* B2 = B1 + NB;
    float* C1 = B2 + NB;
    float* C2 = C1 + NB;
    float* edge = C2 + NB;               // 4*2304
    float* vbuf = edge + 4 * HW;         // 3*4*2304*8
    float* rbuf = vbuf + 3 * 4 * HW * 8; // 3*4*2304
    float* attb = rbuf + 3 * 4 * HW;     // 3*4*2304*8

    edge_kernel<<<36, 256, 0, stream>>>(x3, edge);
    zero_kernel<<<216, 256, 0, stream>>>((float4*)attb);

    conv_first<144><<<1152, 256, 0, stream>>>(x1, Wc1, bc1, bnf_g, bnf_b, bnf_m, bnf_v, A1);
    conv_first<21><<<1152, 256, 0, stream>>>(x2, Wc2, bc2, bnf_g + 64, bnf_b + 64, bnf_m + 64, bnf_v + 64, B1);
    conv_first<1><<<1152, 256, 0, stream>>>(x3, Wc3, bc3, bnf_g + 128, bnf_b + 128, bnf_m + 128, bnf_v + 128, C1);

    conv64_3<<<3456, 256, 0, stream>>>(A1, B1, C1, A2, B2, C2, Wm, bm, bnm_g, bnm_b, bnm_m, bnm_v, 0);
    conv64_3<<<3456, 256, 0, stream>>>(A2, B2, C2, A1, B1, C1, Wm, bm, bnm_g, bnm_b, bnm_m, bnm_v, 1);

    value_r_kernel<<<432, 256, 0, stream>>>(A1, B1, C1, Wv, bv, vbuf, rbuf);
    attn_kernel<<<2592, 256, 0, stream>>>(A1, B1, C1, vbuf, rbuf, gam, attb);
    final_kernel<<<6912, 256, 0, stream>>>(A1, B1, C1, attb, Wo, bo, edge, (float*)d_out);
}

// Round 8
// 493.610 us; speedup vs baseline: 2.5841x; 1.9287x over previous
//
#include <hip/hip_runtime.h>

#define HW 2304   // 48*48

typedef short s16x8 __attribute__((ext_vector_type(8)));
typedef float f32x4 __attribute__((ext_vector_type(4)));

static __device__ __forceinline__ unsigned short f2bf(float f) {
    unsigned u = __float_as_uint(f);
    unsigned r = (u + 0x7FFFu + ((u >> 16) & 1u)) >> 16;   // RNE
    return (unsigned short)r;
}

// ---------------------------------------------------------------------------
// Zero the attention accumulator (attn_kernel atomically adds partials).
// ---------------------------------------------------------------------------
__global__ __launch_bounds__(256) void zero_kernel(float4* __restrict__ p) {
    p[blockIdx.x * 256 + threadIdx.x] = make_float4(0.f, 0.f, 0.f, 0.f);
}

// ---------------------------------------------------------------------------
// Sobel edge magnitude on x3 (C=1), SAME zero padding.  [4,48,48] -> [4,2304]
// ---------------------------------------------------------------------------
__global__ __launch_bounds__(256) void edge_kernel(const float* __restrict__ x3,
                                                   float* __restrict__ edge) {
    int idx = blockIdx.x * 256 + threadIdx.x;   // < 9216
    int b = idx / HW;
    int j = idx % HW;
    int y = j / 48, x = j % 48;
    const float* p = x3 + b * HW;
    auto at = [&](int yy, int xx) -> float {
        return (yy >= 0 && yy < 48 && xx >= 0 && xx < 48) ? p[yy * 48 + xx] : 0.f;
    };
    float a00 = at(y - 1, x - 1), a01 = at(y - 1, x), a02 = at(y - 1, x + 1);
    float a10 = at(y, x - 1),                         a12 = at(y, x + 1);
    float a20 = at(y + 1, x - 1), a21 = at(y + 1, x), a22 = at(y + 1, x + 1);
    float ex = (a02 - a00) + 2.f * (a12 - a10) + (a22 - a20);
    float ey = (a20 - a00) + 2.f * (a21 - a01) + (a22 - a02);
    edge[idx] = sqrtf(ex * ex + ey * ey);
}

// ---------------------------------------------------------------------------
// conv3x3 + BN(eval) + LeakyReLU body.  (unchanged from R5)
// ---------------------------------------------------------------------------
template <int CIN>
__device__ __forceinline__ void conv_body(
    const float* __restrict__ in, const float* __restrict__ w,
    const float* __restrict__ bias,
    const float* __restrict__ bng, const float* __restrict__ bnb,
    const float* __restrict__ bnm, const float* __restrict__ bnv,
    float* __restrict__ out, int cg, int tile, int b) {
    const int tx0 = (tile % 3) * 16, ty0 = (tile / 3) * 16;
    const int tid = threadIdx.x;
    const int tx = tid & 15, ty = tid >> 4;

    __shared__ float sl[2][2880];   // [buf][8 cin][18][20]

    int goff[11], loff[11], clv[11];
#pragma unroll
    for (int t = 0; t < 11; ++t) {
        int e = tid + t * 256;
        int cl = e / 324; int r = e - cl * 324;
        int ly = r / 18;  int lx = r - ly * 18;
        int gy = ty0 + ly - 1, gx = tx0 + lx - 1;
        bool live = (e < 2592);
        bool inb = live && gy >= 0 && gy < 48 && gx >= 0 && gx < 48;
        goff[t] = inb ? (gy * 48 + gx) : -1;
        loff[t] = live ? (cl * 360 + ly * 20 + lx) : -1;
        clv[t] = cl;
    }

    auto stage = [&](int c0, int bf) {
#pragma unroll
        for (int t = 0; t < 11; ++t) {
            if (loff[t] >= 0) {
                int cin = c0 + clv[t];
                float v = 0.f;
                if (goff[t] >= 0 && (CIN % 8 == 0 || cin < CIN))
                    v = in[(b * CIN + cin) * HW + goff[t]];
                sl[bf][loff[t]] = v;
            }
        }
    };

    float acc[2] = {0.f, 0.f};

    auto compute = [&](int c0, int bf) {
#pragma unroll
        for (int cl = 0; cl < 8; ++cl) {
            if (CIN % 8 != 0 && c0 + cl >= CIN) continue;
            float xv[9];
#pragma unroll
            for (int dy = 0; dy < 3; dy++)
#pragma unroll
                for (int dx = 0; dx < 3; dx++)
                    xv[dy * 3 + dx] = sl[bf][cl * 360 + (ty + dy) * 20 + (tx + dx)];
#pragma unroll
            for (int k = 0; k < 2; ++k) {
                const float* wk = w + ((cg * 2 + k) * CIN + (c0 + cl)) * 9;
                float a = acc[k];
#pragma unroll
                for (int d = 0; d < 9; ++d) a = fmaf(wk[d], xv[d], a);
                acc[k] = a;
            }
        }
    };

    constexpr int NCH = (CIN + 7) / 8;
    stage(0, 0);
    __syncthreads();
#pragma unroll 1
    for (int ch = 0; ch < NCH; ++ch) {
        if (ch + 1 < NCH) stage((ch + 1) * 8, (ch + 1) & 1);
        compute(ch * 8, ch & 1);
        __syncthreads();
    }

    const int oy = ty0 + ty, ox = tx0 + tx;
#pragma unroll
    for (int k = 0; k < 2; ++k) {
        int o = cg * 2 + k;
        float sc = bng[o] * rsqrtf(bnv[o] + 1e-5f);
        float sh = bnb[o] - bnm[o] * sc;
        float y = fmaf(acc[k] + bias[o], sc, sh);
        y = y > 0.f ? y : 0.01f * y;
        out[(b * 64 + o) * HW + oy * 48 + ox] = y;
    }
}

template <int CIN>
__global__ __launch_bounds__(256) void conv_first(
    const float* __restrict__ in, const float* __restrict__ w,
    const float* __restrict__ bias,
    const float* __restrict__ bng, const float* __restrict__ bnb,
    const float* __restrict__ bnm, const float* __restrict__ bnv,
    float* __restrict__ out) {
    int lb = blockIdx.x;
    int blk = (lb & 7) * 144 + (lb >> 3);
    int cg = blk & 31, tile = (blk >> 5) % 9, b = blk / 288;
    conv_body<CIN>(in, w, bias, bng, bnb, bnm, bnv, out, cg, tile, b);
}

__global__ __launch_bounds__(256) void conv64_3(
    const float* __restrict__ inA, const float* __restrict__ inB,
    const float* __restrict__ inC, float* __restrict__ outA,
    float* __restrict__ outB, float* __restrict__ outC,
    const float* __restrict__ Wm, const float* __restrict__ bm,
    const float* __restrict__ bng, const float* __restrict__ bnb,
    const float* __restrict__ bnm, const float* __restrict__ bnv, int step) {
    int lb = blockIdx.x;
    int blk = (lb & 7) * 432 + (lb >> 3);
    int br = blk / 1152;
    int rr = blk - br * 1152;
    int cg = rr & 31, tile = (rr >> 5) % 9, b = rr / 288;
    const float* in = (br == 0) ? inA : (br == 1) ? inB : inC;
    float* out = (br == 0) ? outA : (br == 1) ? outB : outC;
    int so = 2 * br + step;
    conv_body<64>(in, Wm + so * (64 * 64 * 9), bm + so * 64,
                  bng + so * 64, bnb + so * 64, bnm + so * 64, bnv + so * 64,
                  out, cg, tile, b);
}

// ---------------------------------------------------------------------------
// value_r_kernel: per-position value vectors (1x1 conv 64->8), squared norms,
// AND the transposed bf16 feature tensor dT[m][b][j][c] (row = 128 B),
// pre-swizzled: 16B-chunk index ^= (j&7)  (so attn can global_load_lds
// linearly and ds_read with the same XOR -> conflict-free MFMA operands).
// ---------------------------------------------------------------------------
__global__ __launch_bounds__(256) void value_r_kernel(
    const float* __restrict__ d1, const float* __restrict__ d2,
    const float* __restrict__ d3, const float* __restrict__ Wv,
    const float* __restrict__ bv, float* __restrict__ vbuf,
    float* __restrict__ rbuf, unsigned short* __restrict__ dT) {
    __shared__ float sWv[512];
    int blk = blockIdx.x;
    int jseg = blk % 36;
    int b = (blk / 36) % 4;
    int m = blk / 144;
    int tid = threadIdx.x;
    sWv[tid] = Wv[tid];
    if (tid < 256) sWv[tid + 256] = Wv[tid + 256];
    __syncthreads();

    int jl = tid >> 2, cp = tid & 3;
    int j = jseg * 64 + jl;
    const float* dm = (m == 0) ? d1 : (m == 1) ? d2 : d3;
    const float* dp = dm + (b * 64) * HW + j;
    float acc[8];
#pragma unroll
    for (int k = 0; k < 8; k++) acc[k] = 0.f;
    float r = 0.f;
    float x[16];
#pragma unroll
    for (int cc = 0; cc < 16; ++cc) {
        int c = cp * 16 + cc;
        float xv = dp[c * HW];
        x[cc] = xv;
        r = fmaf(xv, xv, r);
#pragma unroll
        for (int k = 0; k < 8; k++) acc[k] = fmaf(xv, sWv[k * 64 + c], acc[k]);
    }

    // ---- dT write: this thread owns c = cp*16 .. cp*16+15 of row j ----
    {
        unsigned wds[8];
#pragma unroll
        for (int t = 0; t < 8; ++t)
            wds[t] = (unsigned)f2bf(x[2 * t]) | ((unsigned)f2bf(x[2 * t + 1]) << 16);
        size_t rowb = ((size_t)(m * 4 + b) * HW + j) * 128;   // bytes
        int s = jl & 7;                                        // == j & 7
        uint4 p0 = make_uint4(wds[0], wds[1], wds[2], wds[3]);
        uint4 p1 = make_uint4(wds[4], wds[5], wds[6], wds[7]);
        *(uint4*)((char*)dT + rowb + (size_t)(((cp * 2) ^ s) * 16)) = p0;
        *(uint4*)((char*)dT + rowb + (size_t)(((cp * 2 + 1) ^ s) * 16)) = p1;
    }

    r += __shfl_xor(r, 1, 4);
    r += __shfl_xor(r, 2, 4);
    float* vp = vbuf + ((m * 4 + b) * HW + j) * 8;
#pragma unroll
    for (int k = 0; k < 8; k++) {
        float v = acc[k];
        v += __shfl_xor(v, 1, 4);
        v += __shfl_xor(v, 2, 4);
        if (cp == 0) vp[k] = v + bv[k];
    }
    if (cp == 0) rbuf[(m * 4 + b) * HW + j] = r;
}

// ---------------------------------------------------------------------------
// attn v4: MFMA Gram + VALU epilogue/PV.
// Grid 2592 = 4b * 72 i-tiles(32) * 9 j-segs(256).  Per 64-j subtile:
//   FjT/Vj/Rj staged via global_load_lds (double-buffered, zero VGPR cost);
//   G^T[j][i] = mfma_16x16x32_bf16(FjT, FiT) -> exp epilogue -> per-lane PV
//   (i on lanes -> only 48 pv VGPRs) -> shfl + LDS reduce -> atomicAdd.
// LDS 75.6 KB -> 2 blocks/CU.  (LDS carve via offsets: hipcc rejects
// pointer-array static initializers into addrspace(3).)
// ---------------------------------------------------------------------------
#define FJT(bi) (smem + (bi) * 24576)
#define VJB(bi) ((float*)(smem + 49152 + (bi) * 6144))
#define RJB(bi) ((float*)(smem + 61440 + (bi) * 768))

__global__ __launch_bounds__(256, 2) void attn_kernel(
    const unsigned short* __restrict__ dT, const float* __restrict__ vbuf,
    const float* __restrict__ rbuf, const float* __restrict__ gam,
    float* __restrict__ attbuf) {
    __shared__ char smem[75648];
    char* FiT = smem + 62976;            // 12288 B
    float* Ri = (float*)(smem + 75264);  // 384 B

    int lb = blockIdx.x;
    int blk = (lb & 7) * 324 + (lb >> 3);
    const int js = blk % 9;
    const int it = (blk / 9) % 72;
    const int b  = blk / 648;
    const int i0 = it * 32;
    const int tid = threadIdx.x;
    const int lane = tid & 63;
    const int wv = tid >> 6;           // wave id == j-quadrant (16 j rows)
    const int l15 = lane & 15, lg = lane >> 4;
    const int swz = l15 & 7;           // row&7 for both FjT (j) and FiT (i) reads

    // ---- stage FiT (12 x 1KB) + Ri (once) ----
#pragma unroll
    for (int t = 0; t < 3; ++t) {
        int ck = wv * 3 + t;                     // 0..11
        int m = ck >> 2; int off = (ck & 3) * 1024;
        const char* src = (const char*)dT +
            ((size_t)((m * 4 + b) * HW + i0) * 128) + off + lane * 16;
        __builtin_amdgcn_global_load_lds((const unsigned int*)src,
                                         (unsigned int*)(FiT + ck * 1024), 16, 0, 0);
    }
    if (tid < 96) {
        int m = tid >> 5, i = tid & 31;
        Ri[m * 32 + i] = rbuf[(m * 4 + b) * HW + i0 + i];
    }

    auto stage_tile = [&](int sub, int bi) {
        const int j0 = (js * 4 + sub) * 64;
#pragma unroll
        for (int t = 0; t < 8; ++t) {
            int idx = t * 4 + wv;                // wave-uniform
            if (idx < 24) {                      // FjT: 24 x 1KB
                int m = idx >> 3; int off = (idx & 7) * 1024;
                const char* src = (const char*)dT +
                    ((size_t)((m * 4 + b) * HW + j0) * 128) + off + lane * 16;
                __builtin_amdgcn_global_load_lds((const unsigned int*)src,
                    (unsigned int*)(FJT(bi) + idx * 1024), 16, 0, 0);
            } else if (idx < 30) {               // Vj: 6 x 1KB
                int c = idx - 24; int m = c >> 1; int off = (c & 1) * 1024;
                const char* src = (const char*)vbuf +
                    ((size_t)((m * 4 + b) * HW + j0) * 32) + off + lane * 16;
                __builtin_amdgcn_global_load_lds((const unsigned int*)src,
                    (unsigned int*)((char*)VJB(bi) + c * 1024), 16, 0, 0);
            }
        }
        if (tid < 192) {
            int m = tid >> 6, jl = tid & 63;
            RJB(bi)[m * 64 + jl] = rbuf[(m * 4 + b) * HW + j0 + jl];
        }
    };

    float g0 = gam[0], g1 = gam[1], g2 = gam[2];
    float inv0 = 1.f / (2.f * g0 * g0);
    float inv1 = 1.f / (2.f * g1 * g1);
    float inv2 = 1.f / (2.f * g2 * g2);
    float g6 = gam[6], g7 = gam[7], g8 = gam[8];
    float c00 = g6,       c01 = g7 + 1.f, c02 = g8 + 1.f;
    float c10 = g6 + 1.f, c11 = g7,       c12 = g8 + 1.f;
    float c20 = g6 + 1.f, c21 = g7 + 1.f, c22 = g8;

    stage_tile(0, 0);
    __syncthreads();    // drains global_load_lds (compiler: vmcnt(0) at barrier)

    // per-lane running i-values: i = l15 + 16*ii
    float ri0[2], ri1[2], ri2[2];
#pragma unroll
    for (int ii = 0; ii < 2; ++ii) {
        ri0[ii] = Ri[0 * 32 + ii * 16 + l15];
        ri1[ii] = Ri[1 * 32 + ii * 16 + l15];
        ri2[ii] = Ri[2 * 32 + ii * 16 + l15];
    }

    float pv[3][2][8];
#pragma unroll
    for (int mp = 0; mp < 3; ++mp)
#pragma unroll
        for (int ii = 0; ii < 2; ++ii)
#pragma unroll
            for (int k = 0; k < 8; ++k) pv[mp][ii][k] = 0.f;

#pragma unroll 1
    for (int sub = 0; sub < 4; ++sub) {
        const int bi = sub & 1;
        if (sub < 3) stage_tile(sub + 1, bi ^ 1);   // issue-before-compute

        // ---- Gram MFMA: G^T[j][i], j = wave quadrant, K = c (2 slabs) ----
        f32x4 g[3][2];
#pragma unroll
        for (int m = 0; m < 3; ++m)
#pragma unroll
            for (int ii = 0; ii < 2; ++ii) g[m][ii] = (f32x4){0.f, 0.f, 0.f, 0.f};

#pragma unroll
        for (int m = 0; m < 3; ++m) {
#pragma unroll
            for (int slab = 0; slab < 2; ++slab) {
                int ch = slab * 4 + lg;
                s16x8 a = *(const s16x8*)(FJT(bi) + m * 8192 +
                            (wv * 16 + l15) * 128 + ((ch ^ swz) * 16));
#pragma unroll
                for (int ii = 0; ii < 2; ++ii) {
                    s16x8 bf = *(const s16x8*)(FiT + m * 4096 +
                                (ii * 16 + l15) * 128 + ((ch ^ swz) * 16));
                    g[m][ii] = __builtin_amdgcn_mfma_f32_16x16x32_bf16(
                        a, bf, g[m][ii], 0, 0, 0);
                }
            }
        }

        // ---- epilogue: D rows j = wv*16 + lg*4 + reg ; cols i = l15+16*ii ----
#pragma unroll
        for (int reg = 0; reg < 4; ++reg) {
            const int jl = wv * 16 + lg * 4 + reg;
            float rj0 = RJB(bi)[0 * 64 + jl];
            float rj1 = RJB(bi)[1 * 64 + jl];
            float rj2 = RJB(bi)[2 * 64 + jl];
            float u0[2], u1[2], u2[2];
#pragma unroll
            for (int ii = 0; ii < 2; ++ii) {
                float t0 = fmaxf(ri0[ii] + rj0 - 2.f * g[0][ii][reg], 0.f);
                float t1 = fmaxf(ri1[ii] + rj1 - 2.f * g[1][ii][reg], 0.f);
                float t2 = fmaxf(ri2[ii] + rj2 - 2.f * g[2][ii][reg], 0.f);
                float a0 = __expf(-t0 * inv0);
                float a1 = __expf(-t1 * inv1);
                float a2 = __expf(-t2 * inv2);
                u0[ii] = fmaf(c00, a0, fmaf(c01, a1, c02 * a2));
                u1[ii] = fmaf(c10, a0, fmaf(c11, a1, c12 * a2));
                u2[ii] = fmaf(c20, a0, fmaf(c21, a1, c22 * a2));
            }
            const float* vp0 = &VJB(bi)[(0 * 64 + jl) * 8];
            const float* vp1 = &VJB(bi)[(1 * 64 + jl) * 8];
            const float* vp2 = &VJB(bi)[(2 * 64 + jl) * 8];
            f32x4 v0a = *(const f32x4*)vp0, v0b = *(const f32x4*)(vp0 + 4);
            f32x4 v1a = *(const f32x4*)vp1, v1b = *(const f32x4*)(vp1 + 4);
            f32x4 v2a = *(const f32x4*)vp2, v2b = *(const f32x4*)(vp2 + 4);
#pragma unroll
            for (int ii = 0; ii < 2; ++ii) {
#pragma unroll
                for (int k = 0; k < 4; ++k) {
                    pv[0][ii][k]     = fmaf(u0[ii], v0a[k], pv[0][ii][k]);
                    pv[0][ii][k + 4] = fmaf(u0[ii], v0b[k], pv[0][ii][k + 4]);
                    pv[1][ii][k]     = fmaf(u1[ii], v1a[k], pv[1][ii][k]);
                    pv[1][ii][k + 4] = fmaf(u1[ii], v1b[k], pv[1][ii][k + 4]);
                    pv[2][ii][k]     = fmaf(u2[ii], v2a[k], pv[2][ii][k]);
                    pv[2][ii][k + 4] = fmaf(u2[ii], v2b[k], pv[2][ii][k + 4]);
                }
            }
        }
        __syncthreads();   // next-buffer loads landed; this buffer free
    }

    // ---- reduce: over lanegroups (same i, different j) then over waves ----
#pragma unroll
    for (int mp = 0; mp < 3; ++mp)
#pragma unroll
        for (int ii = 0; ii < 2; ++ii)
#pragma unroll
            for (int k = 0; k < 8; ++k) {
                float v = pv[mp][ii][k];
                v += __shfl_xor(v, 16);
                v += __shfl_xor(v, 32);
                pv[mp][ii][k] = v;
            }

    float* P2 = (float*)smem;   // reuse FjT area: [wave][32 i][3 m][8 k]
    if (lane < 16) {
#pragma unroll
        for (int ii = 0; ii < 2; ++ii)
#pragma unroll
            for (int mp = 0; mp < 3; ++mp) {
                float* dst = &P2[((wv * 32) + ii * 16 + l15) * 24 + mp * 8];
#pragma unroll
                for (int k = 0; k < 8; ++k) dst[k] = pv[mp][ii][k];
            }
    }
    __syncthreads();
    // 768 items (32 i x 3 m x 8 k) on 256 threads -> strided loop (R7 bug fix)
    for (int e = tid; e < 768; e += 256) {
        int i = e / 24, mk = e % 24, mp = mk >> 3, k = mk & 7;
        float s = P2[(0 * 32 + i) * 24 + mk] + P2[(1 * 32 + i) * 24 + mk] +
                  P2[(2 * 32 + i) * 24 + mk] + P2[(3 * 32 + i) * 24 + mk];
        atomicAdd(&attbuf[((mp * 4 + b) * HW + i0 + i) * 8 + k], s * gam[3 + mp]);
    }
}

// ---------------------------------------------------------------------------
// out[m][b][c][j] = d_m[b][c][j] * (att_m[b][j][:] . Wo[c][:] + bo[c]) + edge[b][j]
// ---------------------------------------------------------------------------
__global__ __launch_bounds__(256) void final_kernel(
    const float* __restrict__ d1, const float* __restrict__ d2,
    const float* __restrict__ d3, const float* __restrict__ attbuf,
    const float* __restrict__ Wo, const float* __restrict__ bo,
    const float* __restrict__ edge, float* __restrict__ out) {
    int blk = blockIdx.x;  // 3*4*64*9 = 6912
    int jt = blk % 9;
    int c = (blk / 9) % 64;
    int b = (blk / (9 * 64)) % 4;
    int m = blk / (9 * 64 * 4);
    int j = jt * 256 + threadIdx.x;
    const float* dm = (m == 0) ? d1 : (m == 1) ? d2 : d3;
    const float* ap = attbuf + ((m * 4 + b) * HW + j) * 8;
    float4 aa = *(const float4*)ap, ab = *(const float4*)(ap + 4);
    float av[8] = {aa.x, aa.y, aa.z, aa.w, ab.x, ab.y, ab.z, ab.w};
    float s = bo[c];
#pragma unroll
    for (int k = 0; k < 8; k++) s = fmaf(av[k], Wo[c * 8 + k], s);
    float val = fmaf(dm[(b * 64 + c) * HW + j], s, edge[b * HW + j]);
    out[((m * 4 + b) * 64 + c) * HW + j] = val;
}

// ---------------------------------------------------------------------------
extern "C" void kernel_launch(void* const* d_in, const int* in_sizes, int n_in,
                              void* d_out, int out_size, void* d_ws, size_t ws_size,
                              hipStream_t stream) {
    (void)in_sizes; (void)n_in; (void)out_size; (void)ws_size;
    const float* x1   = (const float*)d_in[0];
    const float* x2   = (const float*)d_in[1];
    const float* x3   = (const float*)d_in[2];
    const float* Wc1  = (const float*)d_in[3];
    const float* bc1  = (const float*)d_in[4];
    const float* Wc2  = (const float*)d_in[5];
    const float* bc2  = (const float*)d_in[6];
    const float* Wc3  = (const float*)d_in[7];
    const float* bc3  = (const float*)d_in[8];
    const float* bnf_g = (const float*)d_in[9];
    const float* bnf_b = (const float*)d_in[10];
    const float* bnf_m = (const float*)d_in[11];
    const float* bnf_v = (const float*)d_in[12];
    const float* Wm   = (const float*)d_in[13];
    const float* bm   = (const float*)d_in[14];
    const float* bnm_g = (const float*)d_in[15];
    const float* bnm_b = (const float*)d_in[16];
    const float* bnm_m = (const float*)d_in[17];
    const float* bnm_v = (const float*)d_in[18];
    const float* Wv   = (const float*)d_in[19];
    const float* bv   = (const float*)d_in[20];
    const float* Wo   = (const float*)d_in[21];
    const float* bo   = (const float*)d_in[22];
    const float* gam  = (const float*)d_in[23];

    float* ws = (float*)d_ws;
    const int NB = 4 * 64 * HW;
    float* A1 = ws;
    float* A2 = A1 + NB;
    float* B1 = A2 + NB;
    float* B2 = B1 + NB;
    float* C1 = B2 + NB;
    float* C2 = C1 + NB;
    float* edge = C2 + NB;                 // 4*2304
    float* vbuf = edge + 4 * HW;           // 3*4*2304*8
    float* rbuf = vbuf + 3 * 4 * HW * 8;   // 3*4*2304
    float* attb = rbuf + 3 * 4 * HW;       // 3*4*2304*8
    unsigned short* dT = (unsigned short*)(attb + 3 * 4 * HW * 8);  // 3*4*2304*64 bf16

    edge_kernel<<<36, 256, 0, stream>>>(x3, edge);
    zero_kernel<<<216, 256, 0, stream>>>((float4*)attb);

    conv_first<144><<<1152, 256, 0, stream>>>(x1, Wc1, bc1, bnf_g, bnf_b, bnf_m, bnf_v, A1);
    conv_first<21><<<1152, 256, 0, stream>>>(x2, Wc2, bc2, bnf_g + 64, bnf_b + 64, bnf_m + 64, bnf_v + 64, B1);
    conv_first<1><<<1152, 256, 0, stream>>>(x3, Wc3, bc3, bnf_g + 128, bnf_b + 128, bnf_m + 128, bnf_v + 128, C1);

    conv64_3<<<3456, 256, 0, stream>>>(A1, B1, C1, A2, B2, C2, Wm, bm, bnm_g, bnm_b, bnm_m, bnm_v, 0);
    conv64_3<<<3456, 256, 0, stream>>>(A2, B2, C2, A1, B1, C1, Wm, bm, bnm_g, bnm_b, bnm_m, bnm_v, 1);

    value_r_kernel<<<432, 256, 0, stream>>>(A1, B1, C1, Wv, bv, vbuf, rbuf, dT);
    attn_kernel<<<2592, 256, 0, stream>>>(dT, vbuf, rbuf, gam, attb);
    final_kernel<<<6912, 256, 0, stream>>>(A1, B1, C1, attb, Wo, bo, edge, (float*)d_out);
}

// Round 9
// 459.532 us; speedup vs baseline: 2.7758x; 1.0742x over previous
//
#include <hip/hip_runtime.h>

#define HW 2304   // 48*48

typedef short s16x8 __attribute__((ext_vector_type(8)));
typedef float f32x4 __attribute__((ext_vector_type(4)));

static __device__ __forceinline__ unsigned short f2bf(float f) {
    unsigned u = __float_as_uint(f);
    unsigned r = (u + 0x7FFFu + ((u >> 16) & 1u)) >> 16;   // RNE
    return (unsigned short)r;
}

// ---------------------------------------------------------------------------
// Zero the attention accumulator (attn_kernel atomically adds partials).
// ---------------------------------------------------------------------------
__global__ __launch_bounds__(256) void zero_kernel(float4* __restrict__ p) {
    p[blockIdx.x * 256 + threadIdx.x] = make_float4(0.f, 0.f, 0.f, 0.f);
}

// ---------------------------------------------------------------------------
// Sobel edge magnitude on x3 (C=1), SAME zero padding.  [4,48,48] -> [4,2304]
// ---------------------------------------------------------------------------
__global__ __launch_bounds__(256) void edge_kernel(const float* __restrict__ x3,
                                                   float* __restrict__ edge) {
    int idx = blockIdx.x * 256 + threadIdx.x;   // < 9216
    int b = idx / HW;
    int j = idx % HW;
    int y = j / 48, x = j % 48;
    const float* p = x3 + b * HW;
    auto at = [&](int yy, int xx) -> float {
        return (yy >= 0 && yy < 48 && xx >= 0 && xx < 48) ? p[yy * 48 + xx] : 0.f;
    };
    float a00 = at(y - 1, x - 1), a01 = at(y - 1, x), a02 = at(y - 1, x + 1);
    float a10 = at(y, x - 1),                         a12 = at(y, x + 1);
    float a20 = at(y + 1, x - 1), a21 = at(y + 1, x), a22 = at(y + 1, x + 1);
    float ex = (a02 - a00) + 2.f * (a12 - a10) + (a22 - a20);
    float ey = (a20 - a00) + 2.f * (a21 - a01) + (a22 - a02);
    edge[idx] = sqrtf(ex * ex + ey * ey);
}

// ---------------------------------------------------------------------------
// conv3x3 + BN(eval) + LeakyReLU body.  16x16 spatial tile, NC couts/block.
// NC raised (R9): the 9 LDS reads/cin/thread feed 2*NC*9 FMAs -> the conv was
// LDS-read-pipe-bound at NC=2 (2.05 GB LDS traffic, 92% pipe busy).
// ---------------------------------------------------------------------------
template <int CIN, int NC>
__device__ __forceinline__ void conv_body(
    const float* __restrict__ in, const float* __restrict__ w,
    const float* __restrict__ bias,
    const float* __restrict__ bng, const float* __restrict__ bnb,
    const float* __restrict__ bnm, const float* __restrict__ bnv,
    float* __restrict__ out, int cg, int tile, int b) {
    const int tx0 = (tile % 3) * 16, ty0 = (tile / 3) * 16;
    const int tid = threadIdx.x;
    const int tx = tid & 15, ty = tid >> 4;

    __shared__ float sl[2][2880];   // [buf][8 cin][18][20]

    int goff[11], loff[11], clv[11];
#pragma unroll
    for (int t = 0; t < 11; ++t) {
        int e = tid + t * 256;
        int cl = e / 324; int r = e - cl * 324;
        int ly = r / 18;  int lx = r - ly * 18;
        int gy = ty0 + ly - 1, gx = tx0 + lx - 1;
        bool live = (e < 2592);
        bool inb = live && gy >= 0 && gy < 48 && gx >= 0 && gx < 48;
        goff[t] = inb ? (gy * 48 + gx) : -1;
        loff[t] = live ? (cl * 360 + ly * 20 + lx) : -1;
        clv[t] = cl;
    }

    auto stage = [&](int c0, int bf) {
#pragma unroll
        for (int t = 0; t < 11; ++t) {
            if (loff[t] >= 0) {
                int cin = c0 + clv[t];
                float v = 0.f;
                if (goff[t] >= 0 && (CIN % 8 == 0 || cin < CIN))
                    v = in[(b * CIN + cin) * HW + goff[t]];
                sl[bf][loff[t]] = v;
            }
        }
    };

    float acc[NC];
#pragma unroll
    for (int k = 0; k < NC; ++k) acc[k] = 0.f;

    auto compute = [&](int c0, int bf) {
#pragma unroll
        for (int cl = 0; cl < 8; ++cl) {
            if (CIN % 8 != 0 && c0 + cl >= CIN) continue;
            float xv[9];
#pragma unroll
            for (int dy = 0; dy < 3; dy++)
#pragma unroll
                for (int dx = 0; dx < 3; dx++)
                    xv[dy * 3 + dx] = sl[bf][cl * 360 + (ty + dy) * 20 + (tx + dx)];
#pragma unroll
            for (int k = 0; k < NC; ++k) {
                const float* wk = w + ((cg * NC + k) * CIN + (c0 + cl)) * 9;
                float a = acc[k];
#pragma unroll
                for (int d = 0; d < 9; ++d) a = fmaf(wk[d], xv[d], a);
                acc[k] = a;
            }
        }
    };

    constexpr int NCH = (CIN + 7) / 8;
    stage(0, 0);
    __syncthreads();
#pragma unroll 1
    for (int ch = 0; ch < NCH; ++ch) {
        if (ch + 1 < NCH) stage((ch + 1) * 8, (ch + 1) & 1);
        compute(ch * 8, ch & 1);
        __syncthreads();
    }

    const int oy = ty0 + ty, ox = tx0 + tx;
#pragma unroll
    for (int k = 0; k < NC; ++k) {
        int o = cg * NC + k;
        float sc = bng[o] * rsqrtf(bnv[o] + 1e-5f);
        float sh = bnb[o] - bnm[o] * sc;
        float y = fmaf(acc[k] + bias[o], sc, sh);
        y = y > 0.f ? y : 0.01f * y;
        out[(b * 64 + o) * HW + oy * 48 + ox] = y;
    }
}

// First-layer convs: NC=4 -> grid 576 = 4b * 9 tiles * 16 cout-groups.
template <int CIN>
__global__ __launch_bounds__(256) void conv_first(
    const float* __restrict__ in, const float* __restrict__ w,
    const float* __restrict__ bias,
    const float* __restrict__ bng, const float* __restrict__ bnb,
    const float* __restrict__ bnm, const float* __restrict__ bnv,
    float* __restrict__ out) {
    int lb = blockIdx.x;
    int blk = (lb & 7) * 72 + (lb >> 3);   // 576 = 8 * 72
    int cg = blk & 15, tile = (blk >> 4) % 9, b = blk / 144;
    conv_body<CIN, 4>(in, w, bias, bng, bnb, bnm, bnv, out, cg, tile, b);
}

// Fused 64->64 convs, NC=8 -> grid 864 = 3 branches * 4b * 9 tiles * 8 groups.
__global__ __launch_bounds__(256) void conv64_3(
    const float* __restrict__ inA, const float* __restrict__ inB,
    const float* __restrict__ inC, float* __restrict__ outA,
    float* __restrict__ outB, float* __restrict__ outC,
    const float* __restrict__ Wm, const float* __restrict__ bm,
    const float* __restrict__ bng, const float* __restrict__ bnb,
    const float* __restrict__ bnm, const float* __restrict__ bnv, int step) {
    int lb = blockIdx.x;
    int blk = (lb & 7) * 108 + (lb >> 3);  // 864 = 8 * 108
    int br = blk / 288;
    int rr = blk - br * 288;
    int cg = rr & 7, tile = (rr >> 3) % 9, b = rr / 72;
    const float* in = (br == 0) ? inA : (br == 1) ? inB : inC;
    float* out = (br == 0) ? outA : (br == 1) ? outB : outC;
    int so = 2 * br + step;
    conv_body<64, 8>(in, Wm + so * (64 * 64 * 9), bm + so * 64,
                     bng + so * 64, bnb + so * 64, bnm + so * 64, bnv + so * 64,
                     out, cg, tile, b);
}

// ---------------------------------------------------------------------------
// value_r_kernel: per-position value vectors (1x1 conv 64->8), squared norms,
// AND the transposed bf16 feature tensor dT[m][b][j][c] (row = 128 B),
// pre-swizzled: 16B-chunk index ^= (j&7).
// ---------------------------------------------------------------------------
__global__ __launch_bounds__(256) void value_r_kernel(
    const float* __restrict__ d1, const float* __restrict__ d2,
    const float* __restrict__ d3, const float* __restrict__ Wv,
    const float* __restrict__ bv, float* __restrict__ vbuf,
    float* __restrict__ rbuf, unsigned short* __restrict__ dT) {
    __shared__ float sWv[512];
    int blk = blockIdx.x;
    int jseg = blk % 36;
    int b = (blk / 36) % 4;
    int m = blk / 144;
    int tid = threadIdx.x;
    sWv[tid] = Wv[tid];
    if (tid < 256) sWv[tid + 256] = Wv[tid + 256];
    __syncthreads();

    int jl = tid >> 2, cp = tid & 3;
    int j = jseg * 64 + jl;
    const float* dm = (m == 0) ? d1 : (m == 1) ? d2 : d3;
    const float* dp = dm + (b * 64) * HW + j;
    float acc[8];
#pragma unroll
    for (int k = 0; k < 8; k++) acc[k] = 0.f;
    float r = 0.f;
    float x[16];
#pragma unroll
    for (int cc = 0; cc < 16; ++cc) {
        int c = cp * 16 + cc;
        float xv = dp[c * HW];
        x[cc] = xv;
        r = fmaf(xv, xv, r);
#pragma unroll
        for (int k = 0; k < 8; k++) acc[k] = fmaf(xv, sWv[k * 64 + c], acc[k]);
    }

    // ---- dT write: this thread owns c = cp*16 .. cp*16+15 of row j ----
    {
        unsigned wds[8];
#pragma unroll
        for (int t = 0; t < 8; ++t)
            wds[t] = (unsigned)f2bf(x[2 * t]) | ((unsigned)f2bf(x[2 * t + 1]) << 16);
        size_t rowb = ((size_t)(m * 4 + b) * HW + j) * 128;   // bytes
        int s = jl & 7;                                        // == j & 7
        uint4 p0 = make_uint4(wds[0], wds[1], wds[2], wds[3]);
        uint4 p1 = make_uint4(wds[4], wds[5], wds[6], wds[7]);
        *(uint4*)((char*)dT + rowb + (size_t)(((cp * 2) ^ s) * 16)) = p0;
        *(uint4*)((char*)dT + rowb + (size_t)(((cp * 2 + 1) ^ s) * 16)) = p1;
    }

    r += __shfl_xor(r, 1, 4);
    r += __shfl_xor(r, 2, 4);
    float* vp = vbuf + ((m * 4 + b) * HW + j) * 8;
#pragma unroll
    for (int k = 0; k < 8; k++) {
        float v = acc[k];
        v += __shfl_xor(v, 1, 4);
        v += __shfl_xor(v, 2, 4);
        if (cp == 0) vp[k] = v + bv[k];
    }
    if (cp == 0) rbuf[(m * 4 + b) * HW + j] = r;
}

// ---------------------------------------------------------------------------
// attn v4: MFMA Gram + VALU epilogue/PV.  (unchanged from R8 — passing)
// ---------------------------------------------------------------------------
#define FJT(bi) (smem + (bi) * 24576)
#define VJB(bi) ((float*)(smem + 49152 + (bi) * 6144))
#define RJB(bi) ((float*)(smem + 61440 + (bi) * 768))

__global__ __launch_bounds__(256, 2) void attn_kernel(
    const unsigned short* __restrict__ dT, const float* __restrict__ vbuf,
    const float* __restrict__ rbuf, const float* __restrict__ gam,
    float* __restrict__ attbuf) {
    __shared__ char smem[75648];
    char* FiT = smem + 62976;            // 12288 B
    float* Ri = (float*)(smem + 75264);  // 384 B

    int lb = blockIdx.x;
    int blk = (lb & 7) * 324 + (lb >> 3);
    const int js = blk % 9;
    const int it = (blk / 9) % 72;
    const int b  = blk / 648;
    const int i0 = it * 32;
    const int tid = threadIdx.x;
    const int lane = tid & 63;
    const int wv = tid >> 6;           // wave id == j-quadrant (16 j rows)
    const int l15 = lane & 15, lg = lane >> 4;
    const int swz = l15 & 7;           // row&7 for both FjT (j) and FiT (i) reads

    // ---- stage FiT (12 x 1KB) + Ri (once) ----
#pragma unroll
    for (int t = 0; t < 3; ++t) {
        int ck = wv * 3 + t;                     // 0..11
        int m = ck >> 2; int off = (ck & 3) * 1024;
        const char* src = (const char*)dT +
            ((size_t)((m * 4 + b) * HW + i0) * 128) + off + lane * 16;
        __builtin_amdgcn_global_load_lds((const unsigned int*)src,
                                         (unsigned int*)(FiT + ck * 1024), 16, 0, 0);
    }
    if (tid < 96) {
        int m = tid >> 5, i = tid & 31;
        Ri[m * 32 + i] = rbuf[(m * 4 + b) * HW + i0 + i];
    }

    auto stage_tile = [&](int sub, int bi) {
        const int j0 = (js * 4 + sub) * 64;
#pragma unroll
        for (int t = 0; t < 8; ++t) {
            int idx = t * 4 + wv;                // wave-uniform
            if (idx < 24) {                      // FjT: 24 x 1KB
                int m = idx >> 3; int off = (idx & 7) * 1024;
                const char* src = (const char*)dT +
                    ((size_t)((m * 4 + b) * HW + j0) * 128) + off + lane * 16;
                __builtin_amdgcn_global_load_lds((const unsigned int*)src,
                    (unsigned int*)(FJT(bi) + idx * 1024), 16, 0, 0);
            } else if (idx < 30) {               // Vj: 6 x 1KB
                int c = idx - 24; int m = c >> 1; int off = (c & 1) * 1024;
                const char* src = (const char*)vbuf +
                    ((size_t)((m * 4 + b) * HW + j0) * 32) + off + lane * 16;
                __builtin_amdgcn_global_load_lds((const unsigned int*)src,
                    (unsigned int*)((char*)VJB(bi) + c * 1024), 16, 0, 0);
            }
        }
        if (tid < 192) {
            int m = tid >> 6, jl = tid & 63;
            RJB(bi)[m * 64 + jl] = rbuf[(m * 4 + b) * HW + j0 + jl];
        }
    };

    float g0 = gam[0], g1 = gam[1], g2 = gam[2];
    float inv0 = 1.f / (2.f * g0 * g0);
    float inv1 = 1.f / (2.f * g1 * g1);
    float inv2 = 1.f / (2.f * g2 * g2);
    float g6 = gam[6], g7 = gam[7], g8 = gam[8];
    float c00 = g6,       c01 = g7 + 1.f, c02 = g8 + 1.f;
    float c10 = g6 + 1.f, c11 = g7,       c12 = g8 + 1.f;
    float c20 = g6 + 1.f, c21 = g7 + 1.f, c22 = g8;

    stage_tile(0, 0);
    __syncthreads();    // drains global_load_lds (compiler: vmcnt(0) at barrier)

    // per-lane running i-values: i = l15 + 16*ii
    float ri0[2], ri1[2], ri2[2];
#pragma unroll
    for (int ii = 0; ii < 2; ++ii) {
        ri0[ii] = Ri[0 * 32 + ii * 16 + l15];
        ri1[ii] = Ri[1 * 32 + ii * 16 + l15];
        ri2[ii] = Ri[2 * 32 + ii * 16 + l15];
    }

    float pv[3][2][8];
#pragma unroll
    for (int mp = 0; mp < 3; ++mp)
#pragma unroll
        for (int ii = 0; ii < 2; ++ii)
#pragma unroll
            for (int k = 0; k < 8; ++k) pv[mp][ii][k] = 0.f;

#pragma unroll 1
    for (int sub = 0; sub < 4; ++sub) {
        const int bi = sub & 1;
        if (sub < 3) stage_tile(sub + 1, bi ^ 1);   // issue-before-compute

        // ---- Gram MFMA: G^T[j][i], j = wave quadrant, K = c (2 slabs) ----
        f32x4 g[3][2];
#pragma unroll
        for (int m = 0; m < 3; ++m)
#pragma unroll
            for (int ii = 0; ii < 2; ++ii) g[m][ii] = (f32x4){0.f, 0.f, 0.f, 0.f};

#pragma unroll
        for (int m = 0; m < 3; ++m) {
#pragma unroll
            for (int slab = 0; slab < 2; ++slab) {
                int ch = slab * 4 + lg;
                s16x8 a = *(const s16x8*)(FJT(bi) + m * 8192 +
                            (wv * 16 + l15) * 128 + ((ch ^ swz) * 16));
#pragma unroll
                for (int ii = 0; ii < 2; ++ii) {
                    s16x8 bf = *(const s16x8*)(FiT + m * 4096 +
                                (ii * 16 + l15) * 128 + ((ch ^ swz) * 16));
                    g[m][ii] = __builtin_amdgcn_mfma_f32_16x16x32_bf16(
                        a, bf, g[m][ii], 0, 0, 0);
                }
            }
        }

        // ---- epilogue: D rows j = wv*16 + lg*4 + reg ; cols i = l15+16*ii ----
#pragma unroll
        for (int reg = 0; reg < 4; ++reg) {
            const int jl = wv * 16 + lg * 4 + reg;
            float rj0 = RJB(bi)[0 * 64 + jl];
            float rj1 = RJB(bi)[1 * 64 + jl];
            float rj2 = RJB(bi)[2 * 64 + jl];
            float u0[2], u1[2], u2[2];
#pragma unroll
            for (int ii = 0; ii < 2; ++ii) {
                float t0 = fmaxf(ri0[ii] + rj0 - 2.f * g[0][ii][reg], 0.f);
                float t1 = fmaxf(ri1[ii] + rj1 - 2.f * g[1][ii][reg], 0.f);
                float t2 = fmaxf(ri2[ii] + rj2 - 2.f * g[2][ii][reg], 0.f);
                float a0 = __expf(-t0 * inv0);
                float a1 = __expf(-t1 * inv1);
                float a2 = __expf(-t2 * inv2);
                u0[ii] = fmaf(c00, a0, fmaf(c01, a1, c02 * a2));
                u1[ii] = fmaf(c10, a0, fmaf(c11, a1, c12 * a2));
                u2[ii] = fmaf(c20, a0, fmaf(c21, a1, c22 * a2));
            }
            const float* vp0 = &VJB(bi)[(0 * 64 + jl) * 8];
            const float* vp1 = &VJB(bi)[(1 * 64 + jl) * 8];
            const float* vp2 = &VJB(bi)[(2 * 64 + jl) * 8];
            f32x4 v0a = *(const f32x4*)vp0, v0b = *(const f32x4*)(vp0 + 4);
            f32x4 v1a = *(const f32x4*)vp1, v1b = *(const f32x4*)(vp1 + 4);
            f32x4 v2a = *(const f32x4*)vp2, v2b = *(const f32x4*)(vp2 + 4);
#pragma unroll
            for (int ii = 0; ii < 2; ++ii) {
#pragma unroll
                for (int k = 0; k < 4; ++k) {
                    pv[0][ii][k]     = fmaf(u0[ii], v0a[k], pv[0][ii][k]);
                    pv[0][ii][k + 4] = fmaf(u0[ii], v0b[k], pv[0][ii][k + 4]);
                    pv[1][ii][k]     = fmaf(u1[ii], v1a[k], pv[1][ii][k]);
                    pv[1][ii][k + 4] = fmaf(u1[ii], v1b[k], pv[1][ii][k + 4]);
                    pv[2][ii][k]     = fmaf(u2[ii], v2a[k], pv[2][ii][k]);
                    pv[2][ii][k + 4] = fmaf(u2[ii], v2b[k], pv[2][ii][k + 4]);
                }
            }
        }
        __syncthreads();   // next-buffer loads landed; this buffer free
    }

    // ---- reduce: over lanegroups (same i, different j) then over waves ----
#pragma unroll
    for (int mp = 0; mp < 3; ++mp)
#pragma unroll
        for (int ii = 0; ii < 2; ++ii)
#pragma unroll
            for (int k = 0; k < 8; ++k) {
                float v = pv[mp][ii][k];
                v += __shfl_xor(v, 16);
                v += __shfl_xor(v, 32);
                pv[mp][ii][k] = v;
            }

    float* P2 = (float*)smem;   // reuse FjT area: [wave][32 i][3 m][8 k]
    if (lane < 16) {
#pragma unroll
        for (int ii = 0; ii < 2; ++ii)
#pragma unroll
            for (int mp = 0; mp < 3; ++mp) {
                float* dst = &P2[((wv * 32) + ii * 16 + l15) * 24 + mp * 8];
#pragma unroll
                for (int k = 0; k < 8; ++k) dst[k] = pv[mp][ii][k];
            }
    }
    __syncthreads();
    // 768 items (32 i x 3 m x 8 k) on 256 threads -> strided loop
    for (int e = tid; e < 768; e += 256) {
        int i = e / 24, mk = e % 24, mp = mk >> 3, k = mk & 7;
        float s = P2[(0 * 32 + i) * 24 + mk] + P2[(1 * 32 + i) * 24 + mk] +
                  P2[(2 * 32 + i) * 24 + mk] + P2[(3 * 32 + i) * 24 + mk];
        atomicAdd(&attbuf[((mp * 4 + b) * HW + i0 + i) * 8 + k], s * gam[3 + mp]);
    }
}

// ---------------------------------------------------------------------------
// out[m][b][c][j] = d_m[b][c][j] * (att_m[b][j][:] . Wo[c][:] + bo[c]) + edge[b][j]
// ---------------------------------------------------------------------------
__global__ __launch_bounds__(256) void final_kernel(
    const float* __restrict__ d1, const float* __restrict__ d2,
    const float* __restrict__ d3, const float* __restrict__ attbuf,
    const float* __restrict__ Wo, const float* __restrict__ bo,
    const float* __restrict__ edge, float* __restrict__ out) {
    int blk = blockIdx.x;  // 3*4*64*9 = 6912
    int jt = blk % 9;
    int c = (blk / 9) % 64;
    int b = (blk / (9 * 64)) % 4;
    int m = blk / (9 * 64 * 4);
    int j = jt * 256 + threadIdx.x;
    const float* dm = (m == 0) ? d1 : (m == 1) ? d2 : d3;
    const float* ap = attbuf + ((m * 4 + b) * HW + j) * 8;
    float4 aa = *(const float4*)ap, ab = *(const float4*)(ap + 4);
    float av[8] = {aa.x, aa.y, aa.z, aa.w, ab.x, ab.y, ab.z, ab.w};
    float s = bo[c];
#pragma unroll
    for (int k = 0; k < 8; k++) s = fmaf(av[k], Wo[c * 8 + k], s);
    float val = fmaf(dm[(b * 64 + c) * HW + j], s, edge[b * HW + j]);
    out[((m * 4 + b) * 64 + c) * HW + j] = val;
}

// ---------------------------------------------------------------------------
extern "C" void kernel_launch(void* const* d_in, const int* in_sizes, int n_in,
                              void* d_out, int out_size, void* d_ws, size_t ws_size,
                              hipStream_t stream) {
    (void)in_sizes; (void)n_in; (void)out_size; (void)ws_size;
    const float* x1   = (const float*)d_in[0];
    const float* x2   = (const float*)d_in[1];
    const float* x3   = (const float*)d_in[2];
    const float* Wc1  = (const float*)d_in[3];
    const float* bc1  = (const float*)d_in[4];
    const float* Wc2  = (const float*)d_in[5];
    const float* bc2  = (const float*)d_in[6];
    const float* Wc3  = (const float*)d_in[7];
    const float* bc3  = (const float*)d_in[8];
    const float* bnf_g = (const float*)d_in[9];
    const float* bnf_b = (const float*)d_in[10];
    const float* bnf_m = (const float*)d_in[11];
    const float* bnf_v = (const float*)d_in[12];
    const float* Wm   = (const float*)d_in[13];
    const float* bm   = (const float*)d_in[14];
    const float* bnm_g = (const float*)d_in[15];
    const float* bnm_b = (const float*)d_in[16];
    const float* bnm_m = (const float*)d_in[17];
    const float* bnm_v = (const float*)d_in[18];
    const float* Wv   = (const float*)d_in[19];
    const float* bv   = (const float*)d_in[20];
    const float* Wo   = (const float*)d_in[21];
    const float* bo   = (const float*)d_in[22];
    const float* gam  = (const float*)d_in[23];

    float* ws = (float*)d_ws;
    const int NB = 4 * 64 * HW;
    float* A1 = ws;
    float* A2 = A1 + NB;
    float* B1 = A2 + NB;
    float* B2 = B1 + NB;
    float* C1 = B2 + NB;
    float* C2 = C1 + NB;
    float* edge = C2 + NB;                 // 4*2304
    float* vbuf = edge + 4 * HW;           // 3*4*2304*8
    float* rbuf = vbuf + 3 * 4 * HW * 8;   // 3*4*2304
    float* attb = rbuf + 3 * 4 * HW;       // 3*4*2304*8
    unsigned short* dT = (unsigned short*)(attb + 3 * 4 * HW * 8);  // 3*4*2304*64 bf16

    edge_kernel<<<36, 256, 0, stream>>>(x3, edge);
    zero_kernel<<<216, 256, 0, stream>>>((float4*)attb);

    conv_first<144><<<576, 256, 0, stream>>>(x1, Wc1, bc1, bnf_g, bnf_b, bnf_m, bnf_v, A1);
    conv_first<21><<<576, 256, 0, stream>>>(x2, Wc2, bc2, bnf_g + 64, bnf_b + 64, bnf_m + 64, bnf_v + 64, B1);
    conv_first<1><<<576, 256, 0, stream>>>(x3, Wc3, bc3, bnf_g + 128, bnf_b + 128, bnf_m + 128, bnf_v + 128, C1);

    conv64_3<<<864, 256, 0, stream>>>(A1, B1, C1, A2, B2, C2, Wm, bm, bnm_g, bnm_b, bnm_m, bnm_v, 0);
    conv64_3<<<864, 256, 0, stream>>>(A2, B2, C2, A1, B1, C1, Wm, bm, bnm_g, bnm_b, bnm_m, bnm_v, 1);

    value_r_kernel<<<432, 256, 0, stream>>>(A1, B1, C1, Wv, bv, vbuf, rbuf, dT);
    attn_kernel<<<2592, 256, 0, stream>>>(dT, vbuf, rbuf, gam, attb);
    final_kernel<<<6912, 256, 0, stream>>>(A1, B1, C1, attb, Wo, bo, edge, (float*)d_out);
}

// Round 10
// 408.315 us; speedup vs baseline: 3.1239x; 1.1254x over previous
//
#include <hip/hip_runtime.h>

#define HW 2304   // 48*48

typedef short s16x8 __attribute__((ext_vector_type(8)));
typedef float f32x4 __attribute__((ext_vector_type(4)));

static __device__ __forceinline__ unsigned short f2bf(float f) {
    unsigned u = __float_as_uint(f);
    unsigned r = (u + 0x7FFFu + ((u >> 16) & 1u)) >> 16;   // RNE
    return (unsigned short)r;
}

// ---------------------------------------------------------------------------
// Zero attb + accX (contiguous): 811008 floats = 202752 float4 -> 792 blocks.
// ---------------------------------------------------------------------------
__global__ __launch_bounds__(256) void zero_kernel(float4* __restrict__ p) {
    p[blockIdx.x * 256 + threadIdx.x] = make_float4(0.f, 0.f, 0.f, 0.f);
}

// ---------------------------------------------------------------------------
// Sobel edge magnitude on x3 (C=1), SAME zero padding.  [4,48,48] -> [4,2304]
// ---------------------------------------------------------------------------
__global__ __launch_bounds__(256) void edge_kernel(const float* __restrict__ x3,
                                                   float* __restrict__ edge) {
    int idx = blockIdx.x * 256 + threadIdx.x;   // < 9216
    int b = idx / HW;
    int j = idx % HW;
    int y = j / 48, x = j % 48;
    const float* p = x3 + b * HW;
    auto at = [&](int yy, int xx) -> float {
        return (yy >= 0 && yy < 48 && xx >= 0 && xx < 48) ? p[yy * 48 + xx] : 0.f;
    };
    float a00 = at(y - 1, x - 1), a01 = at(y - 1, x), a02 = at(y - 1, x + 1);
    float a10 = at(y, x - 1),                         a12 = at(y, x + 1);
    float a20 = at(y + 1, x - 1), a21 = at(y + 1, x), a22 = at(y + 1, x + 1);
    float ex = (a02 - a00) + 2.f * (a12 - a10) + (a22 - a20);
    float ey = (a20 - a00) + 2.f * (a21 - a01) + (a22 - a02);
    edge[idx] = sqrtf(ex * ex + ey * ey);
}

// ---------------------------------------------------------------------------
// conv3x3 + BN(eval) + LeakyReLU body (full-CIN path; used for CIN 21/1/64).
// ---------------------------------------------------------------------------
template <int CIN, int NC>
__device__ __forceinline__ void conv_body(
    const float* __restrict__ in, const float* __restrict__ w,
    const float* __restrict__ bias,
    const float* __restrict__ bng, const float* __restrict__ bnb,
    const float* __restrict__ bnm, const float* __restrict__ bnv,
    float* __restrict__ out, int cg, int tile, int b) {
    const int tx0 = (tile % 3) * 16, ty0 = (tile / 3) * 16;
    const int tid = threadIdx.x;
    const int tx = tid & 15, ty = tid >> 4;

    __shared__ float sl[2][2880];   // [buf][8 cin][18][20]

    int goff[11], loff[11], clv[11];
#pragma unroll
    for (int t = 0; t < 11; ++t) {
        int e = tid + t * 256;
        int cl = e / 324; int r = e - cl * 324;
        int ly = r / 18;  int lx = r - ly * 18;
        int gy = ty0 + ly - 1, gx = tx0 + lx - 1;
        bool live = (e < 2592);
        bool inb = live && gy >= 0 && gy < 48 && gx >= 0 && gx < 48;
        goff[t] = inb ? (gy * 48 + gx) : -1;
        loff[t] = live ? (cl * 360 + ly * 20 + lx) : -1;
        clv[t] = cl;
    }

    auto stage = [&](int c0, int bf) {
#pragma unroll
        for (int t = 0; t < 11; ++t) {
            if (loff[t] >= 0) {
                int cin = c0 + clv[t];
                float v = 0.f;
                if (goff[t] >= 0 && (CIN % 8 == 0 || cin < CIN))
                    v = in[(b * CIN + cin) * HW + goff[t]];
                sl[bf][loff[t]] = v;
            }
        }
    };

    float acc[NC];
#pragma unroll
    for (int k = 0; k < NC; ++k) acc[k] = 0.f;

    auto compute = [&](int c0, int bf) {
#pragma unroll
        for (int cl = 0; cl < 8; ++cl) {
            if (CIN % 8 != 0 && c0 + cl >= CIN) continue;
            float xv[9];
#pragma unroll
            for (int dy = 0; dy < 3; dy++)
#pragma unroll
                for (int dx = 0; dx < 3; dx++)
                    xv[dy * 3 + dx] = sl[bf][cl * 360 + (ty + dy) * 20 + (tx + dx)];
#pragma unroll
            for (int k = 0; k < NC; ++k) {
                const float* wk = w + ((cg * NC + k) * CIN + (c0 + cl)) * 9;
                float a = acc[k];
#pragma unroll
                for (int d = 0; d < 9; ++d) a = fmaf(wk[d], xv[d], a);
                acc[k] = a;
            }
        }
    };

    constexpr int NCH = (CIN + 7) / 8;
    stage(0, 0);
    __syncthreads();
#pragma unroll 1
    for (int ch = 0; ch < NCH; ++ch) {
        if (ch + 1 < NCH) stage((ch + 1) * 8, (ch + 1) & 1);
        compute(ch * 8, ch & 1);
        __syncthreads();
    }

    const int oy = ty0 + ty, ox = tx0 + tx;
#pragma unroll
    for (int k = 0; k < NC; ++k) {
        int o = cg * NC + k;
        float sc = bng[o] * rsqrtf(bnv[o] + 1e-5f);
        float sh = bnb[o] - bnm[o] * sc;
        float y = fmaf(acc[k] + bias[o], sc, sh);
        y = y > 0.f ? y : 0.01f * y;
        out[(b * 64 + o) * HW + oy * 48 + ox] = y;
    }
}

// Small first-layer convs (CIN 21/1): NC=4 -> grid 576.
template <int CIN>
__global__ __launch_bounds__(256) void conv_first(
    const float* __restrict__ in, const float* __restrict__ w,
    const float* __restrict__ bias,
    const float* __restrict__ bng, const float* __restrict__ bnb,
    const float* __restrict__ bnm, const float* __restrict__ bnv,
    float* __restrict__ out) {
    int lb = blockIdx.x;
    int blk = (lb & 7) * 72 + (lb >> 3);   // 576 = 8 * 72
    int cg = blk & 15, tile = (blk >> 4) % 9, b = blk / 144;
    conv_body<CIN, 4>(in, w, bias, bng, bnb, bnm, bnv, out, cg, tile, b);
}

// ---------------------------------------------------------------------------
// conv144_split (R10): the 144-cin conv was stage-latency-bound at 2.25
// blocks/CU (118 us, VALUBusy 16%).  4-way cin-split x NC=8 -> grid 1152
// (4.5 blk/CU), raw partial sums atomicAdd'ed into zeroed accX; BN applied
// by bn1_kernel afterwards.
// ---------------------------------------------------------------------------
__global__ __launch_bounds__(256) void conv144_split(
    const float* __restrict__ in, const float* __restrict__ w,
    float* __restrict__ acc_out) {
    int lb = blockIdx.x;
    int blk = (lb & 7) * 144 + (lb >> 3);   // 1152 = 8 * 144
    const int sp   = blk & 3;               // cin split (36 each)
    const int cg   = (blk >> 2) & 7;        // cout group of 8
    const int tile = (blk >> 5) % 9;
    const int b    = blk / 288;
    const int tx0 = (tile % 3) * 16, ty0 = (tile / 3) * 16;
    const int tid = threadIdx.x;
    const int tx = tid & 15, ty = tid >> 4;

    __shared__ float sl[2][2880];

    int goff[11], loff[11], clv[11];
#pragma unroll
    for (int t = 0; t < 11; ++t) {
        int e = tid + t * 256;
        int cl = e / 324; int r = e - cl * 324;
        int ly = r / 18;  int lx = r - ly * 18;
        int gy = ty0 + ly - 1, gx = tx0 + lx - 1;
        bool live = (e < 2592);
        bool inb = live && gy >= 0 && gy < 48 && gx >= 0 && gx < 48;
        goff[t] = inb ? (gy * 48 + gx) : -1;
        loff[t] = live ? (cl * 360 + ly * 20 + lx) : -1;
        clv[t] = cl;
    }

    const float* inb_p = in + (b * 144 + sp * 36) * HW;

    auto stage = [&](int c0, int bf) {
#pragma unroll
        for (int t = 0; t < 11; ++t) {
            if (loff[t] >= 0) {
                int cin = c0 + clv[t];
                float v = 0.f;
                if (goff[t] >= 0 && cin < 36) v = inb_p[cin * HW + goff[t]];
                sl[bf][loff[t]] = v;
            }
        }
    };

    float acc[8];
#pragma unroll
    for (int k = 0; k < 8; ++k) acc[k] = 0.f;

    auto compute = [&](int c0, int bf) {
#pragma unroll
        for (int cl = 0; cl < 8; ++cl) {
            if (c0 + cl >= 36) continue;
            float xv[9];
#pragma unroll
            for (int dy = 0; dy < 3; dy++)
#pragma unroll
                for (int dx = 0; dx < 3; dx++)
                    xv[dy * 3 + dx] = sl[bf][cl * 360 + (ty + dy) * 20 + (tx + dx)];
#pragma unroll
            for (int k = 0; k < 8; ++k) {
                const float* wk = w + ((cg * 8 + k) * 144 + sp * 36 + c0 + cl) * 9;
                float a = acc[k];
#pragma unroll
                for (int d = 0; d < 9; ++d) a = fmaf(wk[d], xv[d], a);
                acc[k] = a;
            }
        }
    };

    stage(0, 0);
    __syncthreads();
#pragma unroll 1
    for (int ch = 0; ch < 5; ++ch) {       // 36 cins = 5 chunks (last = 4)
        if (ch + 1 < 5) stage((ch + 1) * 8, (ch + 1) & 1);
        compute(ch * 8, ch & 1);
        __syncthreads();
    }

    const int oy = ty0 + ty, ox = tx0 + tx;
#pragma unroll
    for (int k = 0; k < 8; ++k)
        atomicAdd(&acc_out[(b * 64 + cg * 8 + k) * HW + oy * 48 + ox], acc[k]);
}

// BN + LeakyReLU for the accumulated 144-conv.  589824 elems -> 2304 blocks.
__global__ __launch_bounds__(256) void bn1_kernel(
    const float* __restrict__ acc, const float* __restrict__ bias,
    const float* __restrict__ bng, const float* __restrict__ bnb,
    const float* __restrict__ bnm, const float* __restrict__ bnv,
    float* __restrict__ out) {
    int idx = blockIdx.x * 256 + threadIdx.x;
    int o = (idx / HW) & 63;
    float sc = bng[o] * rsqrtf(bnv[o] + 1e-5f);
    float sh = bnb[o] - bnm[o] * sc;
    float y = fmaf(acc[idx] + bias[o], sc, sh);
    out[idx] = y > 0.f ? y : 0.01f * y;
}

// Fused 64->64 convs, NC=8 -> grid 864 = 3 branches * 4b * 9 tiles * 8 groups.
__global__ __launch_bounds__(256) void conv64_3(
    const float* __restrict__ inA, const float* __restrict__ inB,
    const float* __restrict__ inC, float* __restrict__ outA,
    float* __restrict__ outB, float* __restrict__ outC,
    const float* __restrict__ Wm, const float* __restrict__ bm,
    const float* __restrict__ bng, const float* __restrict__ bnb,
    const float* __restrict__ bnm, const float* __restrict__ bnv, int step) {
    int lb = blockIdx.x;
    int blk = (lb & 7) * 108 + (lb >> 3);  // 864 = 8 * 108
    int br = blk / 288;
    int rr = blk - br * 288;
    int cg = rr & 7, tile = (rr >> 3) % 9, b = rr / 72;
    const float* in = (br == 0) ? inA : (br == 1) ? inB : inC;
    float* out = (br == 0) ? outA : (br == 1) ? outB : outC;
    int so = 2 * br + step;
    conv_body<64, 8>(in, Wm + so * (64 * 64 * 9), bm + so * 64,
                     bng + so * 64, bnb + so * 64, bnm + so * 64, bnv + so * 64,
                     out, cg, tile, b);
}

// ---------------------------------------------------------------------------
// value_r_kernel: value vectors (1x1 conv 64->8), squared norms, and the
// pre-swizzled transposed bf16 feature tensor dT[m][b][j][c] (row = 128 B).
// ---------------------------------------------------------------------------
__global__ __launch_bounds__(256) void value_r_kernel(
    const float* __restrict__ d1, const float* __restrict__ d2,
    const float* __restrict__ d3, const float* __restrict__ Wv,
    const float* __restrict__ bv, float* __restrict__ vbuf,
    float* __restrict__ rbuf, unsigned short* __restrict__ dT) {
    __shared__ float sWv[512];
    int blk = blockIdx.x;
    int jseg = blk % 36;
    int b = (blk / 36) % 4;
    int m = blk / 144;
    int tid = threadIdx.x;
    sWv[tid] = Wv[tid];
    if (tid < 256) sWv[tid + 256] = Wv[tid + 256];
    __syncthreads();

    int jl = tid >> 2, cp = tid & 3;
    int j = jseg * 64 + jl;
    const float* dm = (m == 0) ? d1 : (m == 1) ? d2 : d3;
    const float* dp = dm + (b * 64) * HW + j;
    float acc[8];
#pragma unroll
    for (int k = 0; k < 8; k++) acc[k] = 0.f;
    float r = 0.f;
    float x[16];
#pragma unroll
    for (int cc = 0; cc < 16; ++cc) {
        int c = cp * 16 + cc;
        float xv = dp[c * HW];
        x[cc] = xv;
        r = fmaf(xv, xv, r);
#pragma unroll
        for (int k = 0; k < 8; k++) acc[k] = fmaf(xv, sWv[k * 64 + c], acc[k]);
    }

    {
        unsigned wds[8];
#pragma unroll
        for (int t = 0; t < 8; ++t)
            wds[t] = (unsigned)f2bf(x[2 * t]) | ((unsigned)f2bf(x[2 * t + 1]) << 16);
        size_t rowb = ((size_t)(m * 4 + b) * HW + j) * 128;   // bytes
        int s = jl & 7;                                        // == j & 7
        uint4 p0 = make_uint4(wds[0], wds[1], wds[2], wds[3]);
        uint4 p1 = make_uint4(wds[4], wds[5], wds[6], wds[7]);
        *(uint4*)((char*)dT + rowb + (size_t)(((cp * 2) ^ s) * 16)) = p0;
        *(uint4*)((char*)dT + rowb + (size_t)(((cp * 2 + 1) ^ s) * 16)) = p1;
    }

    r += __shfl_xor(r, 1, 4);
    r += __shfl_xor(r, 2, 4);
    float* vp = vbuf + ((m * 4 + b) * HW + j) * 8;
#pragma unroll
    for (int k = 0; k < 8; k++) {
        float v = acc[k];
        v += __shfl_xor(v, 1, 4);
        v += __shfl_xor(v, 2, 4);
        if (cp == 0) vp[k] = v + bv[k];
    }
    if (cp == 0) rbuf[(m * 4 + b) * HW + j] = r;
}

// ---------------------------------------------------------------------------
// attn v4: MFMA Gram + VALU epilogue/PV.  (unchanged — passing)
// ---------------------------------------------------------------------------
#define FJT(bi) (smem + (bi) * 24576)
#define VJB(bi) ((float*)(smem + 49152 + (bi) * 6144))
#define RJB(bi) ((float*)(smem + 61440 + (bi) * 768))

__global__ __launch_bounds__(256, 2) void attn_kernel(
    const unsigned short* __restrict__ dT, const float* __restrict__ vbuf,
    const float* __restrict__ rbuf, const float* __restrict__ gam,
    float* __restrict__ attbuf) {
    __shared__ char smem[75648];
    char* FiT = smem + 62976;            // 12288 B
    float* Ri = (float*)(smem + 75264);  // 384 B

    int lb = blockIdx.x;
    int blk = (lb & 7) * 324 + (lb >> 3);
    const int js = blk % 9;
    const int it = (blk / 9) % 72;
    const int b  = blk / 648;
    const int i0 = it * 32;
    const int tid = threadIdx.x;
    const int lane = tid & 63;
    const int wv = tid >> 6;
    const int l15 = lane & 15, lg = lane >> 4;
    const int swz = l15 & 7;

    // ---- stage FiT (12 x 1KB) + Ri (once) ----
#pragma unroll
    for (int t = 0; t < 3; ++t) {
        int ck = wv * 3 + t;
        int m = ck >> 2; int off = (ck & 3) * 1024;
        const char* src = (const char*)dT +
            ((size_t)((m * 4 + b) * HW + i0) * 128) + off + lane * 16;
        __builtin_amdgcn_global_load_lds((const unsigned int*)src,
                                         (unsigned int*)(FiT + ck * 1024), 16, 0, 0);
    }
    if (tid < 96) {
        int m = tid >> 5, i = tid & 31;
        Ri[m * 32 + i] = rbuf[(m * 4 + b) * HW + i0 + i];
    }

    auto stage_tile = [&](int sub, int bi) {
        const int j0 = (js * 4 + sub) * 64;
#pragma unroll
        for (int t = 0; t < 8; ++t) {
            int idx = t * 4 + wv;
            if (idx < 24) {
                int m = idx >> 3; int off = (idx & 7) * 1024;
                const char* src = (const char*)dT +
                    ((size_t)((m * 4 + b) * HW + j0) * 128) + off + lane * 16;
                __builtin_amdgcn_global_load_lds((const unsigned int*)src,
                    (unsigned int*)(FJT(bi) + idx * 1024), 16, 0, 0);
            } else if (idx < 30) {
                int c = idx - 24; int m = c >> 1; int off = (c & 1) * 1024;
                const char* src = (const char*)vbuf +
                    ((size_t)((m * 4 + b) * HW + j0) * 32) + off + lane * 16;
                __builtin_amdgcn_global_load_lds((const unsigned int*)src,
                    (unsigned int*)((char*)VJB(bi) + c * 1024), 16, 0, 0);
            }
        }
        if (tid < 192) {
            int m = tid >> 6, jl = tid & 63;
            RJB(bi)[m * 64 + jl] = rbuf[(m * 4 + b) * HW + j0 + jl];
        }
    };

    float g0 = gam[0], g1 = gam[1], g2 = gam[2];
    float inv0 = 1.f / (2.f * g0 * g0);
    float inv1 = 1.f / (2.f * g1 * g1);
    float inv2 = 1.f / (2.f * g2 * g2);
    float g6 = gam[6], g7 = gam[7], g8 = gam[8];
    float c00 = g6,       c01 = g7 + 1.f, c02 = g8 + 1.f;
    float c10 = g6 + 1.f, c11 = g7,       c12 = g8 + 1.f;
    float c20 = g6 + 1.f, c21 = g7 + 1.f, c22 = g8;

    stage_tile(0, 0);
    __syncthreads();

    float ri0[2], ri1[2], ri2[2];
#pragma unroll
    for (int ii = 0; ii < 2; ++ii) {
        ri0[ii] = Ri[0 * 32 + ii * 16 + l15];
        ri1[ii] = Ri[1 * 32 + ii * 16 + l15];
        ri2[ii] = Ri[2 * 32 + ii * 16 + l15];
    }

    float pv[3][2][8];
#pragma unroll
    for (int mp = 0; mp < 3; ++mp)
#pragma unroll
        for (int ii = 0; ii < 2; ++ii)
#pragma unroll
            for (int k = 0; k < 8; ++k) pv[mp][ii][k] = 0.f;

#pragma unroll 1
    for (int sub = 0; sub < 4; ++sub) {
        const int bi = sub & 1;
        if (sub < 3) stage_tile(sub + 1, bi ^ 1);

        f32x4 g[3][2];
#pragma unroll
        for (int m = 0; m < 3; ++m)
#pragma unroll
            for (int ii = 0; ii < 2; ++ii) g[m][ii] = (f32x4){0.f, 0.f, 0.f, 0.f};

#pragma unroll
        for (int m = 0; m < 3; ++m) {
#pragma unroll
            for (int slab = 0; slab < 2; ++slab) {
                int ch = slab * 4 + lg;
                s16x8 a = *(const s16x8*)(FJT(bi) + m * 8192 +
                            (wv * 16 + l15) * 128 + ((ch ^ swz) * 16));
#pragma unroll
                for (int ii = 0; ii < 2; ++ii) {
                    s16x8 bf = *(const s16x8*)(FiT + m * 4096 +
                                (ii * 16 + l15) * 128 + ((ch ^ swz) * 16));
                    g[m][ii] = __builtin_amdgcn_mfma_f32_16x16x32_bf16(
                        a, bf, g[m][ii], 0, 0, 0);
                }
            }
        }

#pragma unroll
        for (int reg = 0; reg < 4; ++reg) {
            const int jl = wv * 16 + lg * 4 + reg;
            float rj0 = RJB(bi)[0 * 64 + jl];
            float rj1 = RJB(bi)[1 * 64 + jl];
            float rj2 = RJB(bi)[2 * 64 + jl];
            float u0[2], u1[2], u2[2];
#pragma unroll
            for (int ii = 0; ii < 2; ++ii) {
                float t0 = fmaxf(ri0[ii] + rj0 - 2.f * g[0][ii][reg], 0.f);
                float t1 = fmaxf(ri1[ii] + rj1 - 2.f * g[1][ii][reg], 0.f);
                float t2 = fmaxf(ri2[ii] + rj2 - 2.f * g[2][ii][reg], 0.f);
                float a0 = __expf(-t0 * inv0);
                float a1 = __expf(-t1 * inv1);
                float a2 = __expf(-t2 * inv2);
                u0[ii] = fmaf(c00, a0, fmaf(c01, a1, c02 * a2));
                u1[ii] = fmaf(c10, a0, fmaf(c11, a1, c12 * a2));
                u2[ii] = fmaf(c20, a0, fmaf(c21, a1, c22 * a2));
            }
            const float* vp0 = &VJB(bi)[(0 * 64 + jl) * 8];
            const float* vp1 = &VJB(bi)[(1 * 64 + jl) * 8];
            const float* vp2 = &VJB(bi)[(2 * 64 + jl) * 8];
            f32x4 v0a = *(const f32x4*)vp0, v0b = *(const f32x4*)(vp0 + 4);
            f32x4 v1a = *(const f32x4*)vp1, v1b = *(const f32x4*)(vp1 + 4);
            f32x4 v2a = *(const f32x4*)vp2, v2b = *(const f32x4*)(vp2 + 4);
#pragma unroll
            for (int ii = 0; ii < 2; ++ii) {
#pragma unroll
                for (int k = 0; k < 4; ++k) {
                    pv[0][ii][k]     = fmaf(u0[ii], v0a[k], pv[0][ii][k]);
                    pv[0][ii][k + 4] = fmaf(u0[ii], v0b[k], pv[0][ii][k + 4]);
                    pv[1][ii][k]     = fmaf(u1[ii], v1a[k], pv[1][ii][k]);
                    pv[1][ii][k + 4] = fmaf(u1[ii], v1b[k], pv[1][ii][k + 4]);
                    pv[2][ii][k]     = fmaf(u2[ii], v2a[k], pv[2][ii][k]);
                    pv[2][ii][k + 4] = fmaf(u2[ii], v2b[k], pv[2][ii][k + 4]);
                }
            }
        }
        __syncthreads();
    }

#pragma unroll
    for (int mp = 0; mp < 3; ++mp)
#pragma unroll
        for (int ii = 0; ii < 2; ++ii)
#pragma unroll
            for (int k = 0; k < 8; ++k) {
                float v = pv[mp][ii][k];
                v += __shfl_xor(v, 16);
                v += __shfl_xor(v, 32);
                pv[mp][ii][k] = v;
            }

    float* P2 = (float*)smem;   // reuse FjT area: [wave][32 i][3 m][8 k]
    if (lane < 16) {
#pragma unroll
        for (int ii = 0; ii < 2; ++ii)
#pragma unroll
            for (int mp = 0; mp < 3; ++mp) {
                float* dst = &P2[((wv * 32) + ii * 16 + l15) * 24 + mp * 8];
#pragma unroll
                for (int k = 0; k < 8; ++k) dst[k] = pv[mp][ii][k];
            }
    }
    __syncthreads();
    for (int e = tid; e < 768; e += 256) {
        int i = e / 24, mk = e % 24, mp = mk >> 3, k = mk & 7;
        float s = P2[(0 * 32 + i) * 24 + mk] + P2[(1 * 32 + i) * 24 + mk] +
                  P2[(2 * 32 + i) * 24 + mk] + P2[(3 * 32 + i) * 24 + mk];
        atomicAdd(&attbuf[((mp * 4 + b) * HW + i0 + i) * 8 + k], s * gam[3 + mp]);
    }
}

// ---------------------------------------------------------------------------
// out[m][b][c][j] = d_m[b][c][j] * (att_m[b][j][:] . Wo[c][:] + bo[c]) + edge[b][j]
// ---------------------------------------------------------------------------
__global__ __launch_bounds__(256) void final_kernel(
    const float* __restrict__ d1, const float* __restrict__ d2,
    const float* __restrict__ d3, const float* __restrict__ attbuf,
    const float* __restrict__ Wo, const float* __restrict__ bo,
    const float* __restrict__ edge, float* __restrict__ out) {
    int blk = blockIdx.x;  // 3*4*64*9 = 6912
    int jt = blk % 9;
    int c = (blk / 9) % 64;
    int b = (blk / (9 * 64)) % 4;
    int m = blk / (9 * 64 * 4);
    int j = jt * 256 + threadIdx.x;
    const float* dm = (m == 0) ? d1 : (m == 1) ? d2 : d3;
    const float* ap = attbuf + ((m * 4 + b) * HW + j) * 8;
    float4 aa = *(const float4*)ap, ab = *(const float4*)(ap + 4);
    float av[8] = {aa.x, aa.y, aa.z, aa.w, ab.x, ab.y, ab.z, ab.w};
    float s = bo[c];
#pragma unroll
    for (int k = 0; k < 8; k++) s = fmaf(av[k], Wo[c * 8 + k], s);
    float val = fmaf(dm[(b * 64 + c) * HW + j], s, edge[b * HW + j]);
    out[((m * 4 + b) * 64 + c) * HW + j] = val;
}

// ---------------------------------------------------------------------------
extern "C" void kernel_launch(void* const* d_in, const int* in_sizes, int n_in,
                              void* d_out, int out_size, void* d_ws, size_t ws_size,
                              hipStream_t stream) {
    (void)in_sizes; (void)n_in; (void)out_size; (void)ws_size;
    const float* x1   = (const float*)d_in[0];
    const float* x2   = (const float*)d_in[1];
    const float* x3   = (const float*)d_in[2];
    const float* Wc1  = (const float*)d_in[3];
    const float* bc1  = (const float*)d_in[4];
    const float* Wc2  = (const float*)d_in[5];
    const float* bc2  = (const float*)d_in[6];
    const float* Wc3  = (const float*)d_in[7];
    const float* bc3  = (const float*)d_in[8];
    const float* bnf_g = (const float*)d_in[9];
    const float* bnf_b = (const float*)d_in[10];
    const float* bnf_m = (const float*)d_in[11];
    const float* bnf_v = (const float*)d_in[12];
    const float* Wm   = (const float*)d_in[13];
    const float* bm   = (const float*)d_in[14];
    const float* bnm_g = (const float*)d_in[15];
    const float* bnm_b = (const float*)d_in[16];
    const float* bnm_m = (const float*)d_in[17];
    const float* bnm_v = (const float*)d_in[18];
    const float* Wv   = (const float*)d_in[19];
    const float* bv   = (const float*)d_in[20];
    const float* Wo   = (const float*)d_in[21];
    const float* bo   = (const float*)d_in[22];
    const float* gam  = (const float*)d_in[23];

    float* ws = (float*)d_ws;
    const int NB = 4 * 64 * HW;
    float* A1 = ws;
    float* A2 = A1 + NB;
    float* B1 = A2 + NB;
    float* B2 = B1 + NB;
    float* C1 = B2 + NB;
    float* C2 = C1 + NB;
    float* edge = C2 + NB;                 // 4*2304
    float* vbuf = edge + 4 * HW;           // 3*4*2304*8
    float* rbuf = vbuf + 3 * 4 * HW * 8;   // 3*4*2304
    float* attb = rbuf + 3 * 4 * HW;       // 3*4*2304*8 = 221184
    float* accX = attb + 3 * 4 * HW * 8;   // 4*64*2304 = 589824 (raw conv144 sums)
    unsigned short* dT = (unsigned short*)(accX + NB);  // 3*4*2304*64 bf16

    edge_kernel<<<36, 256, 0, stream>>>(x3, edge);
    // zero attb + accX (contiguous, 811008 floats = 792 * 256 * float4)
    zero_kernel<<<792, 256, 0, stream>>>((float4*)attb);

    conv144_split<<<1152, 256, 0, stream>>>(x1, Wc1, accX);
    conv_first<21><<<576, 256, 0, stream>>>(x2, Wc2, bc2, bnf_g + 64, bnf_b + 64, bnf_m + 64, bnf_v + 64, B1);
    conv_first<1><<<576, 256, 0, stream>>>(x3, Wc3, bc3, bnf_g + 128, bnf_b + 128, bnf_m + 128, bnf_v + 128, C1);
    bn1_kernel<<<2304, 256, 0, stream>>>(accX, bc1, bnf_g, bnf_b, bnf_m, bnf_v, A1);

    conv64_3<<<864, 256, 0, stream>>>(A1, B1, C1, A2, B2, C2, Wm, bm, bnm_g, bnm_b, bnm_m, bnm_v, 0);
    conv64_3<<<864, 256, 0, stream>>>(A2, B2, C2, A1, B1, C1, Wm, bm, bnm_g, bnm_b, bnm_m, bnm_v, 1);

    value_r_kernel<<<432, 256, 0, stream>>>(A1, B1, C1, Wv, bv, vbuf, rbuf, dT);
    attn_kernel<<<2592, 256, 0, stream>>>(dT, vbuf, rbuf, gam, attb);
    final_kernel<<<6912, 256, 0, stream>>>(A1, B1, C1, attb, Wo, bo, edge, (float*)d_out);
}

// Round 11
// 404.124 us; speedup vs baseline: 3.1563x; 1.0104x over previous
//
#include <hip/hip_runtime.h>

#define HW 2304   // 48*48
#define NB (4 * 64 * HW)

typedef short s16x8 __attribute__((ext_vector_type(8)));
typedef float f32x4 __attribute__((ext_vector_type(4)));

static __device__ __forceinline__ unsigned short f2bf(float f) {
    unsigned u = __float_as_uint(f);
    unsigned r = (u + 0x7FFFu + ((u >> 16) & 1u)) >> 16;   // RNE
    return (unsigned short)r;
}

// ---------------------------------------------------------------------------
// Zero attb + accX + accA + accB (contiguous): 4349952 floats = 4248 blocks.
// ---------------------------------------------------------------------------
__global__ __launch_bounds__(256) void zero_kernel(float4* __restrict__ p) {
    p[blockIdx.x * 256 + threadIdx.x] = make_float4(0.f, 0.f, 0.f, 0.f);
}

// ---------------------------------------------------------------------------
// Sobel edge magnitude on x3 (C=1), SAME zero padding.  [4,48,48] -> [4,2304]
// ---------------------------------------------------------------------------
__global__ __launch_bounds__(256) void edge_kernel(const float* __restrict__ x3,
                                                   float* __restrict__ edge) {
    int idx = blockIdx.x * 256 + threadIdx.x;   // < 9216
    int b = idx / HW;
    int j = idx % HW;
    int y = j / 48, x = j % 48;
    const float* p = x3 + b * HW;
    auto at = [&](int yy, int xx) -> float {
        return (yy >= 0 && yy < 48 && xx >= 0 && xx < 48) ? p[yy * 48 + xx] : 0.f;
    };
    float a00 = at(y - 1, x - 1), a01 = at(y - 1, x), a02 = at(y - 1, x + 1);
    float a10 = at(y, x - 1),                         a12 = at(y, x + 1);
    float a20 = at(y + 1, x - 1), a21 = at(y + 1, x), a22 = at(y + 1, x + 1);
    float ex = (a02 - a00) + 2.f * (a12 - a10) + (a22 - a20);
    float ey = (a20 - a00) + 2.f * (a21 - a01) + (a22 - a02);
    edge[idx] = sqrtf(ex * ex + ey * ey);
}

// ---------------------------------------------------------------------------
// conv3x3 + BN(eval) + LeakyReLU body (full-CIN path; used for CIN 21/1).
// ---------------------------------------------------------------------------
template <int CIN, int NC>
__device__ __forceinline__ void conv_body(
    const float* __restrict__ in, const float* __restrict__ w,
    const float* __restrict__ bias,
    const float* __restrict__ bng, const float* __restrict__ bnb,
    const float* __restrict__ bnm, const float* __restrict__ bnv,
    float* __restrict__ out, int cg, int tile, int b) {
    const int tx0 = (tile % 3) * 16, ty0 = (tile / 3) * 16;
    const int tid = threadIdx.x;
    const int tx = tid & 15, ty = tid >> 4;

    __shared__ float sl[2][2880];   // [buf][8 cin][18][20]

    int goff[11], loff[11], clv[11];
#pragma unroll
    for (int t = 0; t < 11; ++t) {
        int e = tid + t * 256;
        int cl = e / 324; int r = e - cl * 324;
        int ly = r / 18;  int lx = r - ly * 18;
        int gy = ty0 + ly - 1, gx = tx0 + lx - 1;
        bool live = (e < 2592);
        bool inb = live && gy >= 0 && gy < 48 && gx >= 0 && gx < 48;
        goff[t] = inb ? (gy * 48 + gx) : -1;
        loff[t] = live ? (cl * 360 + ly * 20 + lx) : -1;
        clv[t] = cl;
    }

    auto stage = [&](int c0, int bf) {
#pragma unroll
        for (int t = 0; t < 11; ++t) {
            if (loff[t] >= 0) {
                int cin = c0 + clv[t];
                float v = 0.f;
                if (goff[t] >= 0 && (CIN % 8 == 0 || cin < CIN))
                    v = in[(b * CIN + cin) * HW + goff[t]];
                sl[bf][loff[t]] = v;
            }
        }
    };

    float acc[NC];
#pragma unroll
    for (int k = 0; k < NC; ++k) acc[k] = 0.f;

    auto compute = [&](int c0, int bf) {
#pragma unroll
        for (int cl = 0; cl < 8; ++cl) {
            if (CIN % 8 != 0 && c0 + cl >= CIN) continue;
            float xv[9];
#pragma unroll
            for (int dy = 0; dy < 3; dy++)
#pragma unroll
                for (int dx = 0; dx < 3; dx++)
                    xv[dy * 3 + dx] = sl[bf][cl * 360 + (ty + dy) * 20 + (tx + dx)];
#pragma unroll
            for (int k = 0; k < NC; ++k) {
                const float* wk = w + ((cg * NC + k) * CIN + (c0 + cl)) * 9;
                float a = acc[k];
#pragma unroll
                for (int d = 0; d < 9; ++d) a = fmaf(wk[d], xv[d], a);
                acc[k] = a;
            }
        }
    };

    constexpr int NCH = (CIN + 7) / 8;
    stage(0, 0);
    __syncthreads();
#pragma unroll 1
    for (int ch = 0; ch < NCH; ++ch) {
        if (ch + 1 < NCH) stage((ch + 1) * 8, (ch + 1) & 1);
        compute(ch * 8, ch & 1);
        __syncthreads();
    }

    const int oy = ty0 + ty, ox = tx0 + tx;
#pragma unroll
    for (int k = 0; k < NC; ++k) {
        int o = cg * NC + k;
        float sc = bng[o] * rsqrtf(bnv[o] + 1e-5f);
        float sh = bnb[o] - bnm[o] * sc;
        float y = fmaf(acc[k] + bias[o], sc, sh);
        y = y > 0.f ? y : 0.01f * y;
        out[(b * 64 + o) * HW + oy * 48 + ox] = y;
    }
}

// Small first-layer convs (CIN 21/1): NC=4 -> grid 576.
template <int CIN>
__global__ __launch_bounds__(256) void conv_first(
    const float* __restrict__ in, const float* __restrict__ w,
    const float* __restrict__ bias,
    const float* __restrict__ bng, const float* __restrict__ bnb,
    const float* __restrict__ bnm, const float* __restrict__ bnv,
    float* __restrict__ out) {
    int lb = blockIdx.x;
    int blk = (lb & 7) * 72 + (lb >> 3);   // 576 = 8 * 72
    int cg = blk & 15, tile = (blk >> 4) % 9, b = blk / 144;
    conv_body<CIN, 4>(in, w, bias, bng, bnb, bnm, bnv, out, cg, tile, b);
}

// ---------------------------------------------------------------------------
// conv144_split: 4-way cin-split x NC=8 -> grid 1152, raw partials
// atomicAdd'ed into zeroed accX; BN applied by bn1_kernel afterwards.
// ---------------------------------------------------------------------------
__global__ __launch_bounds__(256) void conv144_split(
    const float* __restrict__ in, const float* __restrict__ w,
    float* __restrict__ acc_out) {
    int lb = blockIdx.x;
    int blk = (lb & 7) * 144 + (lb >> 3);   // 1152 = 8 * 144
    const int sp   = blk & 3;               // cin split (36 each)
    const int cg   = (blk >> 2) & 7;        // cout group of 8
    const int tile = (blk >> 5) % 9;
    const int b    = blk / 288;
    const int tx0 = (tile % 3) * 16, ty0 = (tile / 3) * 16;
    const int tid = threadIdx.x;
    const int tx = tid & 15, ty = tid >> 4;

    __shared__ float sl[2][2880];

    int goff[11], loff[11], clv[11];
#pragma unroll
    for (int t = 0; t < 11; ++t) {
        int e = tid + t * 256;
        int cl = e / 324; int r = e - cl * 324;
        int ly = r / 18;  int lx = r - ly * 18;
        int gy = ty0 + ly - 1, gx = tx0 + lx - 1;
        bool live = (e < 2592);
        bool inb = live && gy >= 0 && gy < 48 && gx >= 0 && gx < 48;
        goff[t] = inb ? (gy * 48 + gx) : -1;
        loff[t] = live ? (cl * 360 + ly * 20 + lx) : -1;
        clv[t] = cl;
    }

    const float* inb_p = in + (b * 144 + sp * 36) * HW;

    auto stage = [&](int c0, int bf) {
#pragma unroll
        for (int t = 0; t < 11; ++t) {
            if (loff[t] >= 0) {
                int cin = c0 + clv[t];
                float v = 0.f;
                if (goff[t] >= 0 && cin < 36) v = inb_p[cin * HW + goff[t]];
                sl[bf][loff[t]] = v;
            }
        }
    };

    float acc[8];
#pragma unroll
    for (int k = 0; k < 8; ++k) acc[k] = 0.f;

    auto compute = [&](int c0, int bf) {
#pragma unroll
        for (int cl = 0; cl < 8; ++cl) {
            if (c0 + cl >= 36) continue;
            float xv[9];
#pragma unroll
            for (int dy = 0; dy < 3; dy++)
#pragma unroll
                for (int dx = 0; dx < 3; dx++)
                    xv[dy * 3 + dx] = sl[bf][cl * 360 + (ty + dy) * 20 + (tx + dx)];
#pragma unroll
            for (int k = 0; k < 8; ++k) {
                const float* wk = w + ((cg * 8 + k) * 144 + sp * 36 + c0 + cl) * 9;
                float a = acc[k];
#pragma unroll
                for (int d = 0; d < 9; ++d) a = fmaf(wk[d], xv[d], a);
                acc[k] = a;
            }
        }
    };

    stage(0, 0);
    __syncthreads();
#pragma unroll 1
    for (int ch = 0; ch < 5; ++ch) {       // 36 cins = 5 chunks (last = 4)
        if (ch + 1 < 5) stage((ch + 1) * 8, (ch + 1) & 1);
        compute(ch * 8, ch & 1);
        __syncthreads();
    }

    const int oy = ty0 + ty, ox = tx0 + tx;
#pragma unroll
    for (int k = 0; k < 8; ++k)
        atomicAdd(&acc_out[(b * 64 + cg * 8 + k) * HW + oy * 48 + ox], acc[k]);
}

// BN + LeakyReLU for the accumulated 144-conv.  589824 elems -> 2304 blocks.
__global__ __launch_bounds__(256) void bn1_kernel(
    const float* __restrict__ acc, const float* __restrict__ bias,
    const float* __restrict__ bng, const float* __restrict__ bnb,
    const float* __restrict__ bnm, const float* __restrict__ bnv,
    float* __restrict__ out) {
    int idx = blockIdx.x * 256 + threadIdx.x;
    int o = (idx / HW) & 63;
    float sc = bng[o] * rsqrtf(bnv[o] + 1e-5f);
    float sh = bnb[o] - bnm[o] * sc;
    float y = fmaf(acc[idx] + bias[o], sc, sh);
    out[idx] = y > 0.f ? y : 0.01f * y;
}

// ---------------------------------------------------------------------------
// conv64_split (R11): mid 64->64 convs were grid-capped at 13.5 waves/CU
// (864 blocks, 77-89us, VALUBusy 24%).  2-way cin-split -> grid 1728
// (27 waves/CU); raw partials atomicAdd'ed into zeroed acc; bn64 finishes.
// ---------------------------------------------------------------------------
__global__ __launch_bounds__(256) void conv64_split(
    const float* __restrict__ inA, const float* __restrict__ inB,
    const float* __restrict__ inC, float* __restrict__ acc_out,
    const float* __restrict__ Wm, int step) {
    int lb = blockIdx.x;
    int blk = (lb & 7) * 216 + (lb >> 3);  // 1728 = 8 * 216
    const int br = blk / 576;
    int rr = blk - br * 576;
    const int sp   = rr & 1;               // cin split (32 each)
    const int cg   = (rr >> 1) & 7;        // cout group of 8
    const int tile = (rr >> 4) % 9;
    const int b    = rr / 144;
    const int tx0 = (tile % 3) * 16, ty0 = (tile / 3) * 16;
    const int tid = threadIdx.x;
    const int tx = tid & 15, ty = tid >> 4;

    const float* in = (br == 0) ? inA : (br == 1) ? inB : inC;
    const float* w = Wm + (2 * br + step) * (64 * 64 * 9);

    __shared__ float sl[2][2880];

    int goff[11], loff[11], clv[11];
#pragma unroll
    for (int t = 0; t < 11; ++t) {
        int e = tid + t * 256;
        int cl = e / 324; int r = e - cl * 324;
        int ly = r / 18;  int lx = r - ly * 18;
        int gy = ty0 + ly - 1, gx = tx0 + lx - 1;
        bool live = (e < 2592);
        bool inb = live && gy >= 0 && gy < 48 && gx >= 0 && gx < 48;
        goff[t] = inb ? (gy * 48 + gx) : -1;
        loff[t] = live ? (cl * 360 + ly * 20 + lx) : -1;
        clv[t] = cl;
    }

    const float* inb_p = in + (b * 64 + sp * 32) * HW;

    auto stage = [&](int c0, int bf) {
#pragma unroll
        for (int t = 0; t < 11; ++t) {
            if (loff[t] >= 0) {
                float v = 0.f;
                if (goff[t] >= 0) v = inb_p[(c0 + clv[t]) * HW + goff[t]];
                sl[bf][loff[t]] = v;
            }
        }
    };

    float acc[8];
#pragma unroll
    for (int k = 0; k < 8; ++k) acc[k] = 0.f;

    auto compute = [&](int c0, int bf) {
#pragma unroll
        for (int cl = 0; cl < 8; ++cl) {
            float xv[9];
#pragma unroll
            for (int dy = 0; dy < 3; dy++)
#pragma unroll
                for (int dx = 0; dx < 3; dx++)
                    xv[dy * 3 + dx] = sl[bf][cl * 360 + (ty + dy) * 20 + (tx + dx)];
#pragma unroll
            for (int k = 0; k < 8; ++k) {
                const float* wk = w + ((cg * 8 + k) * 64 + sp * 32 + c0 + cl) * 9;
                float a = acc[k];
#pragma unroll
                for (int d = 0; d < 9; ++d) a = fmaf(wk[d], xv[d], a);
                acc[k] = a;
            }
        }
    };

    stage(0, 0);
    __syncthreads();
#pragma unroll 1
    for (int ch = 0; ch < 4; ++ch) {       // 32 cins = 4 chunks of 8
        if (ch + 1 < 4) stage((ch + 1) * 8, (ch + 1) & 1);
        compute(ch * 8, ch & 1);
        __syncthreads();
    }

    const int oy = ty0 + ty, ox = tx0 + tx;
    float* dst = acc_out + br * NB + (b * 64 + cg * 8) * HW + oy * 48 + ox;
#pragma unroll
    for (int k = 0; k < 8; ++k)
        atomicAdd(dst + k * HW, acc[k]);
}

// BN + LeakyReLU for the accumulated 64-convs (3 branches).  Grid 6912.
__global__ __launch_bounds__(256) void bn64_kernel(
    const float* __restrict__ acc, const float* __restrict__ bm,
    const float* __restrict__ bng, const float* __restrict__ bnb,
    const float* __restrict__ bnm, const float* __restrict__ bnv, int step,
    float* __restrict__ oA, float* __restrict__ oB, float* __restrict__ oC) {
    int idx = blockIdx.x * 256 + threadIdx.x;   // < 3*NB
    int br = idx / NB;
    int rem = idx - br * NB;
    int oo = (2 * br + step) * 64 + ((rem / HW) & 63);
    float sc = bng[oo] * rsqrtf(bnv[oo] + 1e-5f);
    float sh = bnb[oo] - bnm[oo] * sc;
    float y = fmaf(acc[idx] + bm[oo], sc, sh);
    y = y > 0.f ? y : 0.01f * y;
    float* out = (br == 0) ? oA : (br == 1) ? oB : oC;
    out[rem] = y;
}

// ---------------------------------------------------------------------------
// value_r_kernel: value vectors (1x1 conv 64->8), squared norms, and the
// pre-swizzled transposed bf16 feature tensor dT[m][b][j][c] (row = 128 B).
// ---------------------------------------------------------------------------
__global__ __launch_bounds__(256) void value_r_kernel(
    const float* __restrict__ d1, const float* __restrict__ d2,
    const float* __restrict__ d3, const float* __restrict__ Wv,
    const float* __restrict__ bv, float* __restrict__ vbuf,
    float* __restrict__ rbuf, unsigned short* __restrict__ dT) {
    __shared__ float sWv[512];
    int blk = blockIdx.x;
    int jseg = blk % 36;
    int b = (blk / 36) % 4;
    int m = blk / 144;
    int tid = threadIdx.x;
    sWv[tid] = Wv[tid];
    if (tid < 256) sWv[tid + 256] = Wv[tid + 256];
    __syncthreads();

    int jl = tid >> 2, cp = tid & 3;
    int j = jseg * 64 + jl;
    const float* dm = (m == 0) ? d1 : (m == 1) ? d2 : d3;
    const float* dp = dm + (b * 64) * HW + j;
    float acc[8];
#pragma unroll
    for (int k = 0; k < 8; k++) acc[k] = 0.f;
    float r = 0.f;
    float x[16];
#pragma unroll
    for (int cc = 0; cc < 16; ++cc) {
        int c = cp * 16 + cc;
        float xv = dp[c * HW];
        x[cc] = xv;
        r = fmaf(xv, xv, r);
#pragma unroll
        for (int k = 0; k < 8; k++) acc[k] = fmaf(xv, sWv[k * 64 + c], acc[k]);
    }

    {
        unsigned wds[8];
#pragma unroll
        for (int t = 0; t < 8; ++t)
            wds[t] = (unsigned)f2bf(x[2 * t]) | ((unsigned)f2bf(x[2 * t + 1]) << 16);
        size_t rowb = ((size_t)(m * 4 + b) * HW + j) * 128;   // bytes
        int s = jl & 7;                                        // == j & 7
        uint4 p0 = make_uint4(wds[0], wds[1], wds[2], wds[3]);
        uint4 p1 = make_uint4(wds[4], wds[5], wds[6], wds[7]);
        *(uint4*)((char*)dT + rowb + (size_t)(((cp * 2) ^ s) * 16)) = p0;
        *(uint4*)((char*)dT + rowb + (size_t)(((cp * 2 + 1) ^ s) * 16)) = p1;
    }

    r += __shfl_xor(r, 1, 4);
    r += __shfl_xor(r, 2, 4);
    float* vp = vbuf + ((m * 4 + b) * HW + j) * 8;
#pragma unroll
    for (int k = 0; k < 8; k++) {
        float v = acc[k];
        v += __shfl_xor(v, 1, 4);
        v += __shfl_xor(v, 2, 4);
        if (cp == 0) vp[k] = v + bv[k];
    }
    if (cp == 0) rbuf[(m * 4 + b) * HW + j] = r;
}

// ---------------------------------------------------------------------------
// attn v4: MFMA Gram + VALU epilogue/PV.  (unchanged — passing)
// ---------------------------------------------------------------------------
#define FJT(bi) (smem + (bi) * 24576)
#define VJB(bi) ((float*)(smem + 49152 + (bi) * 6144))
#define RJB(bi) ((float*)(smem + 61440 + (bi) * 768))

__global__ __launch_bounds__(256, 2) void attn_kernel(
    const unsigned short* __restrict__ dT, const float* __restrict__ vbuf,
    const float* __restrict__ rbuf, const float* __restrict__ gam,
    float* __restrict__ attbuf) {
    __shared__ char smem[75648];
    char* FiT = smem + 62976;            // 12288 B
    float* Ri = (float*)(smem + 75264);  // 384 B

    int lb = blockIdx.x;
    int blk = (lb & 7) * 324 + (lb >> 3);
    const int js = blk % 9;
    const int it = (blk / 9) % 72;
    const int b  = blk / 648;
    const int i0 = it * 32;
    const int tid = threadIdx.x;
    const int lane = tid & 63;
    const int wv = tid >> 6;
    const int l15 = lane & 15, lg = lane >> 4;
    const int swz = l15 & 7;

    // ---- stage FiT (12 x 1KB) + Ri (once) ----
#pragma unroll
    for (int t = 0; t < 3; ++t) {
        int ck = wv * 3 + t;
        int m = ck >> 2; int off = (ck & 3) * 1024;
        const char* src = (const char*)dT +
            ((size_t)((m * 4 + b) * HW + i0) * 128) + off + lane * 16;
        __builtin_amdgcn_global_load_lds((const unsigned int*)src,
                                         (unsigned int*)(FiT + ck * 1024), 16, 0, 0);
    }
    if (tid < 96) {
        int m = tid >> 5, i = tid & 31;
        Ri[m * 32 + i] = rbuf[(m * 4 + b) * HW + i0 + i];
    }

    auto stage_tile = [&](int sub, int bi) {
        const int j0 = (js * 4 + sub) * 64;
#pragma unroll
        for (int t = 0; t < 8; ++t) {
            int idx = t * 4 + wv;
            if (idx < 24) {
                int m = idx >> 3; int off = (idx & 7) * 1024;
                const char* src = (const char*)dT +
                    ((size_t)((m * 4 + b) * HW + j0) * 128) + off + lane * 16;
                __builtin_amdgcn_global_load_lds((const unsigned int*)src,
                    (unsigned int*)(FJT(bi) + idx * 1024), 16, 0, 0);
            } else if (idx < 30) {
                int c = idx - 24; int m = c >> 1; int off = (c & 1) * 1024;
                const char* src = (const char*)vbuf +
                    ((size_t)((m * 4 + b) * HW + j0) * 32) + off + lane * 16;
                __builtin_amdgcn_global_load_lds((const unsigned int*)src,
                    (unsigned int*)((char*)VJB(bi) + c * 1024), 16, 0, 0);
            }
        }
        if (tid < 192) {
            int m = tid >> 6, jl = tid & 63;
            RJB(bi)[m * 64 + jl] = rbuf[(m * 4 + b) * HW + j0 + jl];
        }
    };

    float g0 = gam[0], g1 = gam[1], g2 = gam[2];
    float inv0 = 1.f / (2.f * g0 * g0);
    float inv1 = 1.f / (2.f * g1 * g1);
    float inv2 = 1.f / (2.f * g2 * g2);
    float g6 = gam[6], g7 = gam[7], g8 = gam[8];
    float c00 = g6,       c01 = g7 + 1.f, c02 = g8 + 1.f;
    float c10 = g6 + 1.f, c11 = g7,       c12 = g8 + 1.f;
    float c20 = g6 + 1.f, c21 = g7 + 1.f, c22 = g8;

    stage_tile(0, 0);
    __syncthreads();

    float ri0[2], ri1[2], ri2[2];
#pragma unroll
    for (int ii = 0; ii < 2; ++ii) {
        ri0[ii] = Ri[0 * 32 + ii * 16 + l15];
        ri1[ii] = Ri[1 * 32 + ii * 16 + l15];
        ri2[ii] = Ri[2 * 32 + ii * 16 + l15];
    }

    float pv[3][2][8];
#pragma unroll
    for (int mp = 0; mp < 3; ++mp)
#pragma unroll
        for (int ii = 0; ii < 2; ++ii)
#pragma unroll
            for (int k = 0; k < 8; ++k) pv[mp][ii][k] = 0.f;

#pragma unroll 1
    for (int sub = 0; sub < 4; ++sub) {
        const int bi = sub & 1;
        if (sub < 3) stage_tile(sub + 1, bi ^ 1);

        f32x4 g[3][2];
#pragma unroll
        for (int m = 0; m < 3; ++m)
#pragma unroll
            for (int ii = 0; ii < 2; ++ii) g[m][ii] = (f32x4){0.f, 0.f, 0.f, 0.f};

#pragma unroll
        for (int m = 0; m < 3; ++m) {
#pragma unroll
            for (int slab = 0; slab < 2; ++slab) {
                int ch = slab * 4 + lg;
                s16x8 a = *(const s16x8*)(FJT(bi) + m * 8192 +
                            (wv * 16 + l15) * 128 + ((ch ^ swz) * 16));
#pragma unroll
                for (int ii = 0; ii < 2; ++ii) {
                    s16x8 bf = *(const s16x8*)(FiT + m * 4096 +
                                (ii * 16 + l15) * 128 + ((ch ^ swz) * 16));
                    g[m][ii] = __builtin_amdgcn_mfma_f32_16x16x32_bf16(
                        a, bf, g[m][ii], 0, 0, 0);
                }
            }
        }

#pragma unroll
        for (int reg = 0; reg < 4; ++reg) {
            const int jl = wv * 16 + lg * 4 + reg;
            float rj0 = RJB(bi)[0 * 64 + jl];
            float rj1 = RJB(bi)[1 * 64 + jl];
            float rj2 = RJB(bi)[2 * 64 + jl];
            float u0[2], u1[2], u2[2];
#pragma unroll
            for (int ii = 0; ii < 2; ++ii) {
                float t0 = fmaxf(ri0[ii] + rj0 - 2.f * g[0][ii][reg], 0.f);
                float t1 = fmaxf(ri1[ii] + rj1 - 2.f * g[1][ii][reg], 0.f);
                float t2 = fmaxf(ri2[ii] + rj2 - 2.f * g[2][ii][reg], 0.f);
                float a0 = __expf(-t0 * inv0);
                float a1 = __expf(-t1 * inv1);
                float a2 = __expf(-t2 * inv2);
                u0[ii] = fmaf(c00, a0, fmaf(c01, a1, c02 * a2));
                u1[ii] = fmaf(c10, a0, fmaf(c11, a1, c12 * a2));
                u2[ii] = fmaf(c20, a0, fmaf(c21, a1, c22 * a2));
            }
            const float* vp0 = &VJB(bi)[(0 * 64 + jl) * 8];
            const float* vp1 = &VJB(bi)[(1 * 64 + jl) * 8];
            const float* vp2 = &VJB(bi)[(2 * 64 + jl) * 8];
            f32x4 v0a = *(const f32x4*)vp0, v0b = *(const f32x4*)(vp0 + 4);
            f32x4 v1a = *(const f32x4*)vp1, v1b = *(const f32x4*)(vp1 + 4);
            f32x4 v2a = *(const f32x4*)vp2, v2b = *(const f32x4*)(vp2 + 4);
#pragma unroll
            for (int ii = 0; ii < 2; ++ii) {
#pragma unroll
                for (int k = 0; k < 4; ++k) {
                    pv[0][ii][k]     = fmaf(u0[ii], v0a[k], pv[0][ii][k]);
                    pv[0][ii][k + 4] = fmaf(u0[ii], v0b[k], pv[0][ii][k + 4]);
                    pv[1][ii][k]     = fmaf(u1[ii], v1a[k], pv[1][ii][k]);
                    pv[1][ii][k + 4] = fmaf(u1[ii], v1b[k], pv[1][ii][k + 4]);
                    pv[2][ii][k]     = fmaf(u2[ii], v2a[k], pv[2][ii][k]);
                    pv[2][ii][k + 4] = fmaf(u2[ii], v2b[k], pv[2][ii][k + 4]);
                }
            }
        }
        __syncthreads();
    }

#pragma unroll
    for (int mp = 0; mp < 3; ++mp)
#pragma unroll
        for (int ii = 0; ii < 2; ++ii)
#pragma unroll
            for (int k = 0; k < 8; ++k) {
                float v = pv[mp][ii][k];
                v += __shfl_xor(v, 16);
                v += __shfl_xor(v, 32);
                pv[mp][ii][k] = v;
            }

    float* P2 = (float*)smem;   // reuse FjT area: [wave][32 i][3 m][8 k]
    if (lane < 16) {
#pragma unroll
        for (int ii = 0; ii < 2; ++ii)
#pragma unroll
            for (int mp = 0; mp < 3; ++mp) {
                float* dst = &P2[((wv * 32) + ii * 16 + l15) * 24 + mp * 8];
#pragma unroll
                for (int k = 0; k < 8; ++k) dst[k] = pv[mp][ii][k];
            }
    }
    __syncthreads();
    for (int e = tid; e < 768; e += 256) {
        int i = e / 24, mk = e % 24, mp = mk >> 3, k = mk & 7;
        float s = P2[(0 * 32 + i) * 24 + mk] + P2[(1 * 32 + i) * 24 + mk] +
                  P2[(2 * 32 + i) * 24 + mk] + P2[(3 * 32 + i) * 24 + mk];
        atomicAdd(&attbuf[((mp * 4 + b) * HW + i0 + i) * 8 + k], s * gam[3 + mp]);
    }
}

// ---------------------------------------------------------------------------
// out[m][b][c][j] = d_m[b][c][j] * (att_m[b][j][:] . Wo[c][:] + bo[c]) + edge[b][j]
// ---------------------------------------------------------------------------
__global__ __launch_bounds__(256) void final_kernel(
    const float* __restrict__ d1, const float* __restrict__ d2,
    const float* __restrict__ d3, const float* __restrict__ attbuf,
    const float* __restrict__ Wo, const float* __restrict__ bo,
    const float* __restrict__ edge, float* __restrict__ out) {
    int blk = blockIdx.x;  // 3*4*64*9 = 6912
    int jt = blk % 9;
    int c = (blk / 9) % 64;
    int b = (blk / (9 * 64)) % 4;
    int m = blk / (9 * 64 * 4);
    int j = jt * 256 + threadIdx.x;
    const float* dm = (m == 0) ? d1 : (m == 1) ? d2 : d3;
    const float* ap = attbuf + ((m * 4 + b) * HW + j) * 8;
    float4 aa = *(const float4*)ap, ab = *(const float4*)(ap + 4);
    float av[8] = {aa.x, aa.y, aa.z, aa.w, ab.x, ab.y, ab.z, ab.w};
    float s = bo[c];
#pragma unroll
    for (int k = 0; k < 8; k++) s = fmaf(av[k], Wo[c * 8 + k], s);
    float val = fmaf(dm[(b * 64 + c) * HW + j], s, edge[b * HW + j]);
    out[((m * 4 + b) * 64 + c) * HW + j] = val;
}

// ---------------------------------------------------------------------------
extern "C" void kernel_launch(void* const* d_in, const int* in_sizes, int n_in,
                              void* d_out, int out_size, void* d_ws, size_t ws_size,
                              hipStream_t stream) {
    (void)in_sizes; (void)n_in; (void)out_size; (void)ws_size;
    const float* x1   = (const float*)d_in[0];
    const float* x2   = (const float*)d_in[1];
    const float* x3   = (const float*)d_in[2];
    const float* Wc1  = (const float*)d_in[3];
    const float* bc1  = (const float*)d_in[4];
    const float* Wc2  = (const float*)d_in[5];
    const float* bc2  = (const float*)d_in[6];
    const float* Wc3  = (const float*)d_in[7];
    const float* bc3  = (const float*)d_in[8];
    const float* bnf_g = (const float*)d_in[9];
    const float* bnf_b = (const float*)d_in[10];
    const float* bnf_m = (const float*)d_in[11];
    const float* bnf_v = (const float*)d_in[12];
    const float* Wm   = (const float*)d_in[13];
    const float* bm   = (const float*)d_in[14];
    const float* bnm_g = (const float*)d_in[15];
    const float* bnm_b = (const float*)d_in[16];
    const float* bnm_m = (const float*)d_in[17];
    const float* bnm_v = (const float*)d_in[18];
    const float* Wv   = (const float*)d_in[19];
    const float* bv   = (const float*)d_in[20];
    const float* Wo   = (const float*)d_in[21];
    const float* bo   = (const float*)d_in[22];
    const float* gam  = (const float*)d_in[23];

    float* ws = (float*)d_ws;
    float* A1 = ws;
    float* A2 = A1 + NB;
    float* B1 = A2 + NB;
    float* B2 = B1 + NB;
    float* C1 = B2 + NB;
    float* C2 = C1 + NB;
    float* edge = C2 + NB;                 // 4*2304
    float* vbuf = edge + 4 * HW;           // 3*4*2304*8
    float* rbuf = vbuf + 3 * 4 * HW * 8;   // 3*4*2304
    float* attb = rbuf + 3 * 4 * HW;       // 221184  <- zero region starts here
    float* accX = attb + 3 * 4 * HW * 8;   // 589824  (conv144 partials)
    float* accA = accX + NB;               // 3*NB    (conv64 step0 partials)
    float* accB = accA + 3 * NB;           // 3*NB    (conv64 step1 partials)
    unsigned short* dT = (unsigned short*)(accB + 3 * NB);  // 3*4*2304*64 bf16

    edge_kernel<<<36, 256, 0, stream>>>(x3, edge);
    // zero attb+accX+accA+accB: 221184+589824+1769472*2 = 4349952 floats
    zero_kernel<<<4248, 256, 0, stream>>>((float4*)attb);

    conv144_split<<<1152, 256, 0, stream>>>(x1, Wc1, accX);
    conv_first<21><<<576, 256, 0, stream>>>(x2, Wc2, bc2, bnf_g + 64, bnf_b + 64, bnf_m + 64, bnf_v + 64, B1);
    conv_first<1><<<576, 256, 0, stream>>>(x3, Wc3, bc3, bnf_g + 128, bnf_b + 128, bnf_m + 128, bnf_v + 128, C1);
    bn1_kernel<<<2304, 256, 0, stream>>>(accX, bc1, bnf_g, bnf_b, bnf_m, bnf_v, A1);

    conv64_split<<<1728, 256, 0, stream>>>(A1, B1, C1, accA, Wm, 0);
    bn64_kernel<<<6912, 256, 0, stream>>>(accA, bm, bnm_g, bnm_b, bnm_m, bnm_v, 0, A2, B2, C2);
    conv64_split<<<1728, 256, 0, stream>>>(A2, B2, C2, accB, Wm, 1);
    bn64_kernel<<<6912, 256, 0, stream>>>(accB, bm, bnm_g, bnm_b, bnm_m, bnm_v, 1, A1, B1, C1);

    value_r_kernel<<<432, 256, 0, stream>>>(A1, B1, C1, Wv, bv, vbuf, rbuf, dT);
    attn_kernel<<<2592, 256, 0, stream>>>(dT, vbuf, rbuf, gam, attb);
    final_kernel<<<6912, 256, 0, stream>>>(A1, B1, C1, attb, Wo, bo, edge, (float*)d_out);
}